// Round 7
// baseline (1591.229 us; speedup 1.0000x reference)
//
#include <hip/hip_runtime.h>

#define F_IN 128
#define HID 64
#define NCLS 40

#define BK_SHIFT 7
#define TS 128            // nodes per tile/bucket
#define NB_MAX 800        // max buckets (N <= 102400)
#define BCAP 4096         // staged edges per bucket (mean 2048, +45 sigma)
#define LCAP 16           // LDS staging entries per bucket

typedef __attribute__((ext_vector_type(8))) short bf16x8;
typedef __attribute__((ext_vector_type(4))) float f32x4;
typedef __attribute__((ext_vector_type(4))) int int4v;

__device__ __forceinline__ unsigned short f2b(float f) {
    union { float f; unsigned int u; } v; v.f = f;
    unsigned int u = v.u + 0x7FFFu + ((v.u >> 16) & 1u);
    return (unsigned short)(u >> 16);
}
__device__ __forceinline__ float b2f(unsigned short b) {
    union { unsigned int u; float f; } v; v.u = ((unsigned int)b) << 16;
    return v.f;
}

// ---------------- bin: bucket edges by dst tile; LDS-staged chunked flush ----------------
// per-edge cost = 1 LDS atomic + 1 LDS store; global atomics only per 8/16-edge chunk.
__global__ __launch_bounds__(256) void bin_kernel(
    const int* __restrict__ src, const int* __restrict__ dst,
    int* __restrict__ gcur, unsigned* __restrict__ ebuf, int E, int NB)
{
    __shared__ unsigned lbin[NB_MAX * LCAP];   // 51.2 KB
    __shared__ int lcnt[NB_MAX];               // 3.2 KB
    const int tid = threadIdx.x;
    for (int i = tid; i < NB; i += 256) lcnt[i] = 0;
    __syncthreads();

    const int stride = gridDim.x * 256;
    const int rounds = (E + stride - 1) / stride;
    for (int r = 0; r < rounds; r++) {
        int e = blockIdx.x * 256 + tid + r * stride;
        if (e < E) {
            int d = dst[e];
            int s = src[e];
            int bk = d >> BK_SHIFT;
            unsigned w = ((unsigned)(d & (TS - 1)) << 17) | (unsigned)s;
            int pos = atomicAdd(&lcnt[bk], 1);
            if (pos < LCAP) {
                lbin[bk * LCAP + pos] = w;
            } else {
                atomicSub(&lcnt[bk], 1);
                int g = atomicAdd(&gcur[bk], 1);       // rare
                if (g < BCAP) ebuf[(size_t)bk * BCAP + g] = w;
            }
        }
        __syncthreads();
        // flush bins holding >= 8 entries (8 or 16 at a time; 32/64B dense)
        for (int bk = tid; bk < NB; bk += 256) {
            int c = lcnt[bk]; if (c > LCAP) c = LCAP;
            if (c >= 8) {
                int k = (c >= 16) ? 16 : 8;
                int g = atomicAdd(&gcur[bk], k);
                unsigned* dp = ebuf + (size_t)bk * BCAP;
                for (int j = 0; j < k; j++)
                    if (g + j < BCAP) dp[g + j] = lbin[bk * LCAP + j];
                int rem = c - k;
                for (int j = 0; j < rem; j++) lbin[bk * LCAP + j] = lbin[bk * LCAP + k + j];
                lcnt[bk] = rem;
            }
        }
        __syncthreads();
    }
    // tail flush
    for (int bk = tid; bk < NB; bk += 256) {
        int c = lcnt[bk]; if (c > LCAP) c = LCAP;
        if (c > 0) {
            int g = atomicAdd(&gcur[bk], c);
            unsigned* dp = ebuf + (size_t)bk * BCAP;
            for (int j = 0; j < c; j++)
                if (g + j < BCAP) dp[g + j] = lbin[bk * LCAP + j];
        }
    }
}

// ---------------- W prep: Wt[col][k] bf16, col 0-63 = W1l, 64-127 = W1r ----------------
__global__ __launch_bounds__(256) void wprep_kernel(
    const float* __restrict__ W1l, const float* __restrict__ W1r,
    unsigned short* __restrict__ Wt)
{
    const int tid = threadIdx.x;
    for (int i = 0; i < 64; i++) {
        int idx = i * 256 + tid;
        int k = idx >> 7;
        int c = idx & 127;
        float v = (c < 64) ? W1l[k * 64 + c] : W1r[k * 64 + (c - 64)];
        Wt[c * 128 + k] = f2b(v);
    }
}

// ---------------- layer-1 MFMA GEMM: p1b(bf16) = x@W1l, q1 = x@W1r + b1 ----------------
__global__ __launch_bounds__(256) void gemm1_kernel(
    const float* __restrict__ x, const unsigned short* __restrict__ Wt,
    const float* __restrict__ b1,
    unsigned short* __restrict__ p1b, float* __restrict__ q1, int N)
{
    __shared__ alignas(16) unsigned short sW[128 * 136];
    const int tid = threadIdx.x;
    {
        const int4v* Wg = (const int4v*)Wt;
        #pragma unroll
        for (int i = 0; i < 8; i++) {
            int idx16 = i * 256 + tid;
            int c = idx16 >> 4;
            int k8 = idx16 & 15;
            int4v v = Wg[idx16];
            *(int4v*)&sW[c * 136 + k8 * 8] = v;
        }
    }
    __syncthreads();

    const int w = tid >> 6;
    const int lane = tid & 63;
    const int m = lane & 15;
    const int g = lane >> 4;

    const int node0 = blockIdx.x * 64;
    int arow = node0 + w * 16 + m;
    int arow_c = arow < N ? arow : 0;
    const float* xr = x + (size_t)arow_c * F_IN;

    f32x4 acc[8];
    #pragma unroll
    for (int c = 0; c < 8; c++) acc[c] = (f32x4){0.f, 0.f, 0.f, 0.f};

    #pragma unroll
    for (int ks = 0; ks < 4; ks++) {
        const int k0 = ks * 32 + g * 8;
        f32x4 xa = *(const f32x4*)(xr + k0);
        f32x4 xb = *(const f32x4*)(xr + k0 + 4);
        bf16x8 a;
        a[0] = (short)f2b(xa.x); a[1] = (short)f2b(xa.y);
        a[2] = (short)f2b(xa.z); a[3] = (short)f2b(xa.w);
        a[4] = (short)f2b(xb.x); a[5] = (short)f2b(xb.y);
        a[6] = (short)f2b(xb.z); a[7] = (short)f2b(xb.w);
        #pragma unroll
        for (int ct = 0; ct < 8; ct++) {
            bf16x8 b = *(const bf16x8*)&sW[(ct * 16 + m) * 136 + k0];
            acc[ct] = __builtin_amdgcn_mfma_f32_16x16x32_bf16(a, b, acc[ct], 0, 0, 0);
        }
    }

    float bias[4];
    #pragma unroll
    for (int ct = 4; ct < 8; ct++) bias[ct - 4] = b1[(ct - 4) * 16 + m];

    #pragma unroll
    for (int ct = 0; ct < 8; ct++) {
        const int col = ct * 16 + m;
        #pragma unroll
        for (int r = 0; r < 4; r++) {
            int nd = node0 + w * 16 + g * 4 + r;
            if (nd < N) {
                if (col < 64)
                    p1b[(size_t)nd * HID + col] = f2b(acc[ct][r]);
                else
                    q1[(size_t)nd * HID + (col - 64)] = acc[ct][r] + bias[ct - 4];
            }
        }
    }
}

// ---------------- agg1: per-tile LDS accumulate of p1b rows; h = relu(mean + q1) -> hb ----------------
__global__ __launch_bounds__(256) void agg1_kernel(
    const unsigned* __restrict__ ebuf, const int* __restrict__ gcur,
    const unsigned short* __restrict__ p1b, const float* __restrict__ q1,
    unsigned short* __restrict__ hb, int N)
{
    __shared__ float acc[TS * HID];   // 32 KB
    __shared__ int degs[TS];
    const int b = blockIdx.x;
    const int tid = threadIdx.x;
    for (int i = tid; i < TS * HID; i += 256) acc[i] = 0.f;
    if (tid < TS) degs[tid] = 0;
    __syncthreads();

    int cnt = gcur[b]; if (cnt > BCAP) cnt = BCAP;
    const unsigned* eb = ebuf + (size_t)b * BCAP;
    const int f = tid & 63;
    const int wv = tid >> 6;

    for (int base = wv * 4; base < cnt; base += 16) {
        unsigned w[4]; float v[4]; int l[4];
        #pragma unroll
        for (int j = 0; j < 4; j++)
            w[j] = (base + j < cnt) ? eb[base + j] : 0xFFFFFFFFu;
        #pragma unroll
        for (int j = 0; j < 4; j++) {
            if (w[j] != 0xFFFFFFFFu) {
                int s = w[j] & 0x1FFFF;
                l[j] = (w[j] >> 17) & (TS - 1);
                v[j] = b2f(p1b[(size_t)s * HID + f]);
            }
        }
        #pragma unroll
        for (int j = 0; j < 4; j++) {
            if (w[j] != 0xFFFFFFFFu) {
                atomicAdd(&acc[l[j] * HID + f], v[j]);
                if (f == 0) atomicAdd(&degs[l[j]], 1);
            }
        }
    }
    __syncthreads();

    const int node0 = b << BK_SHIFT;
    for (int idx = tid; idx < TS * HID; idx += 256) {
        int ln = idx >> 6, ff = idx & 63;
        int n = node0 + ln;
        if (n < N) {
            float dg = (float)degs[ln]; dg = dg > 1.f ? dg : 1.f;
            float v = acc[idx] / dg + q1[(size_t)n * HID + ff];
            v = v > 0.f ? v : 0.f;
            hb[(size_t)n * HID + ff] = f2b(v);
        }
    }
}

// ---------------- agg2: per-tile LDS accumulate of hb rows; aggh = mean ----------------
__global__ __launch_bounds__(256) void agg2_kernel(
    const unsigned* __restrict__ ebuf, const int* __restrict__ gcur,
    const unsigned short* __restrict__ hb, float* __restrict__ aggh, int N)
{
    __shared__ float acc[TS * HID];
    __shared__ int degs[TS];
    const int b = blockIdx.x;
    const int tid = threadIdx.x;
    for (int i = tid; i < TS * HID; i += 256) acc[i] = 0.f;
    if (tid < TS) degs[tid] = 0;
    __syncthreads();

    int cnt = gcur[b]; if (cnt > BCAP) cnt = BCAP;
    const unsigned* eb = ebuf + (size_t)b * BCAP;
    const int f = tid & 63;
    const int wv = tid >> 6;

    for (int base = wv * 4; base < cnt; base += 16) {
        unsigned w[4]; float v[4]; int l[4];
        #pragma unroll
        for (int j = 0; j < 4; j++)
            w[j] = (base + j < cnt) ? eb[base + j] : 0xFFFFFFFFu;
        #pragma unroll
        for (int j = 0; j < 4; j++) {
            if (w[j] != 0xFFFFFFFFu) {
                int s = w[j] & 0x1FFFF;
                l[j] = (w[j] >> 17) & (TS - 1);
                v[j] = b2f(hb[(size_t)s * HID + f]);
            }
        }
        #pragma unroll
        for (int j = 0; j < 4; j++) {
            if (w[j] != 0xFFFFFFFFu) {
                atomicAdd(&acc[l[j] * HID + f], v[j]);
                if (f == 0) atomicAdd(&degs[l[j]], 1);
            }
        }
    }
    __syncthreads();

    const int node0 = b << BK_SHIFT;
    for (int idx = tid; idx < TS * HID; idx += 256) {
        int ln = idx >> 6, ff = idx & 63;
        int n = node0 + ln;
        if (n < N) {
            float dg = (float)degs[ln]; dg = dg > 1.f ? dg : 1.f;
            aggh[(size_t)n * HID + ff] = acc[idx] / dg;
        }
    }
}

// ---------------- final dense: out = log_softmax(aggh@W2l + h@W2r + b2) ----------------
#define FN_NODES 64
__global__ __launch_bounds__(256) void final_kernel(
    const unsigned short* __restrict__ hb, const float* __restrict__ aggh,
    const float* __restrict__ W2l, const float* __restrict__ W2r,
    const float* __restrict__ b2, float* __restrict__ out, int N)
{
    __shared__ float sWl[HID * NCLS];
    __shared__ float sWr[HID * NCLS];
    __shared__ float sh[FN_NODES * 65];
    __shared__ float sa[FN_NODES * 65];
    const int tid = threadIdx.x;
    for (int i = tid; i < HID * NCLS; i += 256) { sWl[i] = W2l[i]; sWr[i] = W2r[i]; }
    const int node0 = blockIdx.x * FN_NODES;
    for (int i = tid; i < FN_NODES * HID; i += 256) {
        int r = i >> 6, c = i & 63;
        int n = node0 + r;
        sh[r * 65 + c] = (n < N) ? b2f(hb[(size_t)n * HID + c]) : 0.f;
        sa[r * 65 + c] = (n < N) ? aggh[(size_t)n * HID + c] : 0.f;
    }
    __syncthreads();
    const int r = tid >> 2;
    const int g = tid & 3;
    const int n = node0 + r;
    float acc[10];
    #pragma unroll
    for (int i = 0; i < 10; i++) acc[i] = 0.f;
    const float* shr = &sh[r * 65];
    const float* sar = &sa[r * 65];
    #pragma unroll 4
    for (int k = 0; k < HID; k++) {
        float hv = shr[k], av = sar[k];
        #pragma unroll
        for (int i = 0; i < 10; i++) {
            int j = g * 10 + i;
            acc[i] += av * sWl[k * NCLS + j] + hv * sWr[k * NCLS + j];
        }
    }
    float m = -1e30f;
    #pragma unroll
    for (int i = 0; i < 10; i++) { acc[i] += b2[g * 10 + i]; m = fmaxf(m, acc[i]); }
    m = fmaxf(m, __shfl_xor(m, 1, 4));
    m = fmaxf(m, __shfl_xor(m, 2, 4));
    float s = 0.f;
    #pragma unroll
    for (int i = 0; i < 10; i++) s += __expf(acc[i] - m);
    s += __shfl_xor(s, 1, 4);
    s += __shfl_xor(s, 2, 4);
    const float lse = m + __logf(s);
    if (n < N) {
        #pragma unroll
        for (int i = 0; i < 10; i++)
            out[(size_t)n * NCLS + g * 10 + i] = acc[i] - lse;
    }
}

extern "C" void kernel_launch(void* const* d_in, const int* in_sizes, int n_in,
                              void* d_out, int out_size, void* d_ws, size_t ws_size,
                              hipStream_t stream) {
    const float* x   = (const float*)d_in[0];
    const int*   ei  = (const int*)d_in[1];
    const float* W1l = (const float*)d_in[2];
    const float* W1r = (const float*)d_in[3];
    const float* b1  = (const float*)d_in[4];
    const float* W2l = (const float*)d_in[5];
    const float* W2r = (const float*)d_in[6];
    const float* b2  = (const float*)d_in[7];

    const int N = in_sizes[0] / F_IN;
    const int E = in_sizes[1] / 2;
    const int* src = ei;
    const int* dst = ei + E;
    const int NB = (N + TS - 1) >> BK_SHIFT;    // 782 for N=100000 (<= NB_MAX)

    // ---- workspace layout (int elements) ----
    int* wsi = (int*)d_ws;
    int*      gcur = wsi;                                        // NB (+pad)
    unsigned* ebuf = (unsigned*)(wsi + 1024);                    // NB*BCAP words (12.8 MB)
    size_t o = 1024 + (size_t)NB * BCAP;
    o = (o + 63) & ~(size_t)63;
    unsigned short* Wt  = (unsigned short*)(wsi + o);  o += 8192;            // 32 KB
    unsigned short* p1b = (unsigned short*)(wsi + o);  o += (size_t)32 * N;  // 64N bf16
    unsigned short* hb  = (unsigned short*)(wsi + o);  o += (size_t)32 * N;  // 64N bf16
    float* q1   = (float*)(wsi + o);                   // 64N f32 (q1; reused as aggh)
    float* aggh = q1;
    float* out  = (float*)d_out;

    hipMemsetAsync(gcur, 0, 1024 * sizeof(int), stream);

    bin_kernel<<<256, 256, 0, stream>>>(src, dst, gcur, ebuf, E, NB);
    wprep_kernel<<<1, 256, 0, stream>>>(W1l, W1r, Wt);
    gemm1_kernel<<<(N + 63) / 64, 256, 0, stream>>>(x, Wt, b1, p1b, q1, N);
    agg1_kernel<<<NB, 256, 0, stream>>>(ebuf, gcur, p1b, q1, hb, N);
    agg2_kernel<<<NB, 256, 0, stream>>>(ebuf, gcur, hb, aggh, N);
    final_kernel<<<(N + FN_NODES - 1) / FN_NODES, 256, 0, stream>>>(
        hb, aggh, W2l, W2r, b2, out, N);
}

// Round 8
// 310.624 us; speedup vs baseline: 5.1227x; 5.1227x over previous
//
#include <hip/hip_runtime.h>

#define F_IN 128
#define HID 64
#define NCLS 40

#define TSH 7              // tile shift
#define TS  128            // nodes per dst tile
#define NBMAX 800          // max tiles (N <= 102400)
#define GH 800             // ghist stride
#define NW 256             // writer blocks for hist/part

typedef __attribute__((ext_vector_type(8))) short bf16x8;
typedef __attribute__((ext_vector_type(4))) float f32x4;
typedef __attribute__((ext_vector_type(4))) int int4v;

__device__ __forceinline__ unsigned short f2b(float f) {
    union { float f; unsigned int u; } v; v.f = f;
    unsigned int u = v.u + 0x7FFFu + ((v.u >> 16) & 1u);
    return (unsigned short)(u >> 16);
}
__device__ __forceinline__ float b2f(unsigned short b) {
    union { unsigned int u; float f; } v; v.u = ((unsigned int)b) << 16;
    return v.f;
}

// ---------------- K1: per-block histogram over dst tiles ----------------
__global__ __launch_bounds__(256) void hist_kernel(
    const int* __restrict__ dst, int* __restrict__ ghist, int E, int NB)
{
    __shared__ int h[NBMAX];
    const int tid = threadIdx.x;
    for (int i = tid; i < NBMAX; i += 256) h[i] = 0;
    __syncthreads();
    const int chunk = (E + NW - 1) / NW;
    const int lo = blockIdx.x * chunk;
    const int hi = min(E, lo + chunk);
    for (int e = lo + tid; e < hi; e += 256)
        atomicAdd(&h[dst[e] >> TSH], 1);
    __syncthreads();
    for (int bk = tid; bk < NB; bk += 256)
        ghist[blockIdx.x * GH + bk] = h[bk];
}

// ---------------- K2: tile totals ----------------
__global__ __launch_bounds__(256) void btot_kernel(
    const int* __restrict__ ghist, int* __restrict__ btot)
{
    __shared__ int s[256];
    const int bk = blockIdx.x, t = threadIdx.x;
    s[t] = ghist[t * GH + bk];
    __syncthreads();
    for (int off = 128; off > 0; off >>= 1) {
        if (t < off) s[t] += s[t + off];
        __syncthreads();
    }
    if (t == 0) btot[bk] = s[0];
}

// ---------------- K3: serial scan of tile totals -> bbase ----------------
__global__ void bscan_kernel(const int* __restrict__ btot, int* __restrict__ bbase, int NB) {
    if (threadIdx.x == 0 && blockIdx.x == 0) {
        int run = 0;
        for (int i = 0; i < NB; i++) { bbase[i] = run; run += btot[i]; }
        bbase[NB] = run;
    }
}

// ---------------- K4: per-(tile, block) offsets ----------------
__global__ __launch_bounds__(256) void boff_kernel(
    const int* __restrict__ ghist, const int* __restrict__ bbase,
    int* __restrict__ goff)
{
    __shared__ int s[256];
    const int bk = blockIdx.x, t = threadIdx.x;
    const int v = ghist[t * GH + bk];
    s[t] = v;
    __syncthreads();
    for (int off = 1; off < 256; off <<= 1) {
        int u = (t >= off) ? s[t - off] : 0;
        __syncthreads();
        s[t] += u;
        __syncthreads();
    }
    goff[bk * 256 + t] = bbase[bk] + s[t] - v;   // exclusive
}

// ---------------- K5: partition edges into tile-grouped staging ----------------
__global__ __launch_bounds__(256) void part_kernel(
    const int* __restrict__ src, const int* __restrict__ dst,
    const int* __restrict__ goff, unsigned* __restrict__ staging, int E, int NB)
{
    __shared__ int cur[NBMAX];
    const int tid = threadIdx.x;
    const int blk = blockIdx.x;
    for (int bk = tid; bk < NB; bk += 256) cur[bk] = goff[bk * 256 + blk];
    __syncthreads();
    const int chunk = (E + NW - 1) / NW;
    const int lo = blk * chunk;
    const int hi = min(E, lo + chunk);
    for (int e = lo + tid; e < hi; e += 256) {
        int d = dst[e], s = src[e];
        int bk = d >> TSH;
        int p = atomicAdd(&cur[bk], 1);
        staging[p] = ((unsigned)(d & (TS - 1)) << 17) | (unsigned)s;
    }
}

// ---------------- K6: per-tile CSR build (rowptr slice + confined scatter) ----------------
__global__ __launch_bounds__(256) void build_kernel(
    const unsigned* __restrict__ staging, const int* __restrict__ bbase,
    int* __restrict__ rowptr, int* __restrict__ csr, int N)
{
    __shared__ int scnt[TS];
    __shared__ int sscan[TS];
    __shared__ int spos[TS];
    __shared__ int scur[TS];
    const int b = blockIdx.x, tid = threadIdx.x;
    if (tid < TS) { scnt[tid] = 0; scur[tid] = 0; }
    __syncthreads();
    const int seg0 = bbase[b], seg1 = bbase[b + 1];
    const int len = seg1 - seg0;
    const unsigned* st = staging + seg0;
    for (int i = tid; i < len; i += 256)
        atomicAdd(&scnt[(st[i] >> 17) & (TS - 1)], 1);
    __syncthreads();
    if (tid < TS) sscan[tid] = scnt[tid];
    __syncthreads();
    for (int off = 1; off < TS; off <<= 1) {
        int v = (tid < TS && tid >= off) ? sscan[tid - off] : 0;
        __syncthreads();
        if (tid < TS) sscan[tid] += v;
        __syncthreads();
    }
    const int node0 = b << TSH;
    if (tid < TS) {
        int excl = sscan[tid] - scnt[tid];
        spos[tid] = excl;
        int n = node0 + tid;
        if (n <= N) rowptr[n] = seg0 + excl;
    }
    __syncthreads();
    for (int i = tid; i < len; i += 256) {
        unsigned w = st[i];
        int dl = (w >> 17) & (TS - 1);
        int s = (int)(w & 0x1FFFFu);
        int p = atomicAdd(&scur[dl], 1);
        csr[seg0 + spos[dl] + p] = s;
    }
}

// ---------------- W prep: Wt[col][k] bf16, col 0-63 = W1l, 64-127 = W1r ----------------
__global__ __launch_bounds__(256) void wprep_kernel(
    const float* __restrict__ W1l, const float* __restrict__ W1r,
    unsigned short* __restrict__ Wt)
{
    const int tid = threadIdx.x;
    for (int i = 0; i < 64; i++) {
        int idx = i * 256 + tid;
        int k = idx >> 7;
        int c = idx & 127;
        float v = (c < 64) ? W1l[k * 64 + c] : W1r[k * 64 + (c - 64)];
        Wt[c * 128 + k] = f2b(v);
    }
}

// ---------------- layer-1 MFMA GEMM: p1b = bf16(x@W1l), qb = bf16(x@W1r + b1) ----------------
__global__ __launch_bounds__(256) void gemm1_kernel(
    const float* __restrict__ x, const unsigned short* __restrict__ Wt,
    const float* __restrict__ b1,
    unsigned short* __restrict__ p1b, unsigned short* __restrict__ qb, int N)
{
    __shared__ alignas(16) unsigned short sW[128 * 136];
    const int tid = threadIdx.x;
    {
        const int4v* Wg = (const int4v*)Wt;
        #pragma unroll
        for (int i = 0; i < 8; i++) {
            int idx16 = i * 256 + tid;
            int c = idx16 >> 4;
            int k8 = idx16 & 15;
            int4v v = Wg[idx16];
            *(int4v*)&sW[c * 136 + k8 * 8] = v;
        }
    }
    __syncthreads();

    const int w = tid >> 6;
    const int lane = tid & 63;
    const int m = lane & 15;
    const int g = lane >> 4;

    const int node0 = blockIdx.x * 64;
    int arow = node0 + w * 16 + m;
    int arow_c = arow < N ? arow : 0;
    const float* xr = x + (size_t)arow_c * F_IN;

    f32x4 acc[8];
    #pragma unroll
    for (int c = 0; c < 8; c++) acc[c] = (f32x4){0.f, 0.f, 0.f, 0.f};

    #pragma unroll
    for (int ks = 0; ks < 4; ks++) {
        const int k0 = ks * 32 + g * 8;
        f32x4 xa = *(const f32x4*)(xr + k0);
        f32x4 xb = *(const f32x4*)(xr + k0 + 4);
        bf16x8 a;
        a[0] = (short)f2b(xa.x); a[1] = (short)f2b(xa.y);
        a[2] = (short)f2b(xa.z); a[3] = (short)f2b(xa.w);
        a[4] = (short)f2b(xb.x); a[5] = (short)f2b(xb.y);
        a[6] = (short)f2b(xb.z); a[7] = (short)f2b(xb.w);
        #pragma unroll
        for (int ct = 0; ct < 8; ct++) {
            bf16x8 b = *(const bf16x8*)&sW[(ct * 16 + m) * 136 + k0];
            acc[ct] = __builtin_amdgcn_mfma_f32_16x16x32_bf16(a, b, acc[ct], 0, 0, 0);
        }
    }

    float bias[4];
    #pragma unroll
    for (int ct = 4; ct < 8; ct++) bias[ct - 4] = b1[(ct - 4) * 16 + m];

    #pragma unroll
    for (int ct = 0; ct < 8; ct++) {
        const int col = ct * 16 + m;
        #pragma unroll
        for (int r = 0; r < 4; r++) {
            int nd = node0 + w * 16 + g * 4 + r;
            if (nd < N) {
                if (col < 64)
                    p1b[(size_t)nd * HID + col] = f2b(acc[ct][r]);
                else
                    qb[(size_t)nd * HID + (col - 64)] = f2b(acc[ct][r] + bias[ct - 4]);
            }
        }
    }
}

// ---------------- agg1: hb = bf16(relu(mean(p1b[nbrs]) + qb)) ----------------
__global__ __launch_bounds__(256) void agg1_kernel(
    const int* __restrict__ rowptr, const int* __restrict__ csr,
    const unsigned short* __restrict__ p1b, const unsigned short* __restrict__ qb,
    unsigned short* __restrict__ hb, int N)
{
    const int node = (blockIdx.x * 256 + threadIdx.x) >> 6;
    const int f = threadIdx.x & 63;
    if (node >= N) return;
    const int beg = rowptr[node];
    const int end = rowptr[node + 1];
    float s0 = 0.f, s1 = 0.f, s2 = 0.f, s3 = 0.f;
    float s4 = 0.f, s5 = 0.f, s6 = 0.f, s7 = 0.f;
    int j = beg;
    for (; j + 7 < end; j += 8) {
        int i0 = csr[j], i1 = csr[j+1], i2 = csr[j+2], i3 = csr[j+3];
        int i4 = csr[j+4], i5 = csr[j+5], i6 = csr[j+6], i7 = csr[j+7];
        s0 += b2f(p1b[(size_t)i0 * HID + f]);
        s1 += b2f(p1b[(size_t)i1 * HID + f]);
        s2 += b2f(p1b[(size_t)i2 * HID + f]);
        s3 += b2f(p1b[(size_t)i3 * HID + f]);
        s4 += b2f(p1b[(size_t)i4 * HID + f]);
        s5 += b2f(p1b[(size_t)i5 * HID + f]);
        s6 += b2f(p1b[(size_t)i6 * HID + f]);
        s7 += b2f(p1b[(size_t)i7 * HID + f]);
    }
    for (; j < end; j++) s0 += b2f(p1b[(size_t)csr[j] * HID + f]);
    float s = ((s0 + s1) + (s2 + s3)) + ((s4 + s5) + (s6 + s7));
    float dg = (float)(end - beg);
    dg = dg > 1.f ? dg : 1.f;
    float v = s / dg + b2f(qb[(size_t)node * HID + f]);
    v = v > 0.f ? v : 0.f;
    hb[(size_t)node * HID + f] = f2b(v);
}

// ---------------- agg2: agghb = bf16(mean(hb[nbrs])) ----------------
__global__ __launch_bounds__(256) void agg2_kernel(
    const int* __restrict__ rowptr, const int* __restrict__ csr,
    const unsigned short* __restrict__ hb, unsigned short* __restrict__ agghb, int N)
{
    const int node = (blockIdx.x * 256 + threadIdx.x) >> 6;
    const int f = threadIdx.x & 63;
    if (node >= N) return;
    const int beg = rowptr[node];
    const int end = rowptr[node + 1];
    float s0 = 0.f, s1 = 0.f, s2 = 0.f, s3 = 0.f;
    float s4 = 0.f, s5 = 0.f, s6 = 0.f, s7 = 0.f;
    int j = beg;
    for (; j + 7 < end; j += 8) {
        int i0 = csr[j], i1 = csr[j+1], i2 = csr[j+2], i3 = csr[j+3];
        int i4 = csr[j+4], i5 = csr[j+5], i6 = csr[j+6], i7 = csr[j+7];
        s0 += b2f(hb[(size_t)i0 * HID + f]);
        s1 += b2f(hb[(size_t)i1 * HID + f]);
        s2 += b2f(hb[(size_t)i2 * HID + f]);
        s3 += b2f(hb[(size_t)i3 * HID + f]);
        s4 += b2f(hb[(size_t)i4 * HID + f]);
        s5 += b2f(hb[(size_t)i5 * HID + f]);
        s6 += b2f(hb[(size_t)i6 * HID + f]);
        s7 += b2f(hb[(size_t)i7 * HID + f]);
    }
    for (; j < end; j++) s0 += b2f(hb[(size_t)csr[j] * HID + f]);
    float s = ((s0 + s1) + (s2 + s3)) + ((s4 + s5) + (s6 + s7));
    float dg = (float)(end - beg);
    dg = dg > 1.f ? dg : 1.f;
    agghb[(size_t)node * HID + f] = f2b(s / dg);
}

// ---------------- final dense: out = log_softmax(aggh@W2l + h@W2r + b2) ----------------
#define FN_NODES 64
__global__ __launch_bounds__(256) void final_kernel(
    const unsigned short* __restrict__ hb, const unsigned short* __restrict__ agghb,
    const float* __restrict__ W2l, const float* __restrict__ W2r,
    const float* __restrict__ b2, float* __restrict__ out, int N)
{
    __shared__ float sWl[HID * NCLS];
    __shared__ float sWr[HID * NCLS];
    __shared__ float sh[FN_NODES * 65];
    __shared__ float sa[FN_NODES * 65];
    const int tid = threadIdx.x;
    for (int i = tid; i < HID * NCLS; i += 256) { sWl[i] = W2l[i]; sWr[i] = W2r[i]; }
    const int node0 = blockIdx.x * FN_NODES;
    for (int i = tid; i < FN_NODES * HID; i += 256) {
        int r = i >> 6, c = i & 63;
        int n = node0 + r;
        sh[r * 65 + c] = (n < N) ? b2f(hb[(size_t)n * HID + c]) : 0.f;
        sa[r * 65 + c] = (n < N) ? b2f(agghb[(size_t)n * HID + c]) : 0.f;
    }
    __syncthreads();
    const int r = tid >> 2;
    const int g = tid & 3;
    const int n = node0 + r;
    float acc[10];
    #pragma unroll
    for (int i = 0; i < 10; i++) acc[i] = 0.f;
    const float* shr = &sh[r * 65];
    const float* sar = &sa[r * 65];
    #pragma unroll 4
    for (int k = 0; k < HID; k++) {
        float hv = shr[k], av = sar[k];
        #pragma unroll
        for (int i = 0; i < 10; i++) {
            int j = g * 10 + i;
            acc[i] += av * sWl[k * NCLS + j] + hv * sWr[k * NCLS + j];
        }
    }
    float m = -1e30f;
    #pragma unroll
    for (int i = 0; i < 10; i++) { acc[i] += b2[g * 10 + i]; m = fmaxf(m, acc[i]); }
    m = fmaxf(m, __shfl_xor(m, 1, 4));
    m = fmaxf(m, __shfl_xor(m, 2, 4));
    float s = 0.f;
    #pragma unroll
    for (int i = 0; i < 10; i++) s += __expf(acc[i] - m);
    s += __shfl_xor(s, 1, 4);
    s += __shfl_xor(s, 2, 4);
    const float lse = m + __logf(s);
    if (n < N) {
        #pragma unroll
        for (int i = 0; i < 10; i++)
            out[(size_t)n * NCLS + g * 10 + i] = acc[i] - lse;
    }
}

extern "C" void kernel_launch(void* const* d_in, const int* in_sizes, int n_in,
                              void* d_out, int out_size, void* d_ws, size_t ws_size,
                              hipStream_t stream) {
    const float* x   = (const float*)d_in[0];
    const int*   ei  = (const int*)d_in[1];
    const float* W1l = (const float*)d_in[2];
    const float* W1r = (const float*)d_in[3];
    const float* b1  = (const float*)d_in[4];
    const float* W2l = (const float*)d_in[5];
    const float* W2r = (const float*)d_in[6];
    const float* b2  = (const float*)d_in[7];

    const int N = in_sizes[0] / F_IN;
    const int E = in_sizes[1] / 2;
    const int* src = ei;
    const int* dst = ei + E;
    const int NB = (N + TS - 1) >> TSH;    // 782 for N=100000

    // ---- workspace layout (int elements) ----
    int* wsi = (int*)d_ws;
    size_t o = 0;
    int* rowptr = wsi + o;  o += (size_t)N + 64;            // N+1
    int* btot   = wsi + o;  o += 1024;
    int* bbase  = wsi + o;  o += 1024;                      // NB+1
    int* ghist  = wsi + o;  o += (size_t)NW * GH;           // [block][tile]
    int* goff   = wsi + o;  o += (size_t)NBMAX * NW;        // [tile][block]
    o = (o + 63) & ~(size_t)63;
    unsigned* staging = (unsigned*)(wsi + o);  o += E;      // tile-grouped packed edges
    int* csr    = wsi + o;  o += E;
    o = (o + 63) & ~(size_t)63;
    unsigned short* Wt  = (unsigned short*)(wsi + o);  o += 8192;            // 32 KB
    unsigned short* p1b = (unsigned short*)(wsi + o);  o += (size_t)32 * N;  // 64N bf16 (reused as agghb)
    unsigned short* hb  = (unsigned short*)(wsi + o);  o += (size_t)32 * N;  // 64N bf16
    unsigned short* qb  = (unsigned short*)(wsi + o);  o += (size_t)32 * N;  // 64N bf16
    unsigned short* agghb = p1b;     // alias: p1b dead after agg1
    float* out  = (float*)d_out;

    hist_kernel <<<NW, 256, 0, stream>>>(dst, ghist, E, NB);
    btot_kernel <<<NB, 256, 0, stream>>>(ghist, btot);
    bscan_kernel<<<1, 64, 0, stream>>>(btot, bbase, NB);
    boff_kernel <<<NB, 256, 0, stream>>>(ghist, bbase, goff);
    part_kernel <<<NW, 256, 0, stream>>>(src, dst, goff, staging, E, NB);
    build_kernel<<<NB, 256, 0, stream>>>(staging, bbase, rowptr, csr, N);

    wprep_kernel<<<1, 256, 0, stream>>>(W1l, W1r, Wt);
    gemm1_kernel<<<(N + 63) / 64, 256, 0, stream>>>(x, Wt, b1, p1b, qb, N);
    agg1_kernel<<<(N + 3) / 4, 256, 0, stream>>>(rowptr, csr, p1b, qb, hb, N);
    agg2_kernel<<<(N + 3) / 4, 256, 0, stream>>>(rowptr, csr, hb, agghb, N);
    final_kernel<<<(N + FN_NODES - 1) / FN_NODES, 256, 0, stream>>>(
        hb, agghb, W2l, W2r, b2, out, N);
}

// Round 9
// 262.097 us; speedup vs baseline: 6.0711x; 1.1851x over previous
//
#include <hip/hip_runtime.h>

#define F_IN 128
#define HID 64
#define NCLS 40

#define TSH 7              // tile shift
#define TS  128            // nodes per dst tile
#define NBMAX 800          // max tiles (N <= 102400)
#define GH 800             // ghist stride
#define NW 256             // writer blocks for hist/part

typedef __attribute__((ext_vector_type(8))) short bf16x8;
typedef __attribute__((ext_vector_type(4))) float f32x4;
typedef __attribute__((ext_vector_type(4))) int int4v;

__device__ __forceinline__ unsigned short f2b(float f) {
    union { float f; unsigned int u; } v; v.f = f;
    unsigned int u = v.u + 0x7FFFu + ((v.u >> 16) & 1u);
    return (unsigned short)(u >> 16);
}
__device__ __forceinline__ float b2f(unsigned short b) {
    union { unsigned int u; float f; } v; v.u = ((unsigned int)b) << 16;
    return v.f;
}

// ---------------- K1: per-block histogram over dst tiles ----------------
__global__ __launch_bounds__(256) void hist_kernel(
    const int* __restrict__ dst, int* __restrict__ ghist, int E, int NB)
{
    __shared__ int h[NBMAX];
    const int tid = threadIdx.x;
    for (int i = tid; i < NBMAX; i += 256) h[i] = 0;
    __syncthreads();
    const int chunk = (E + NW - 1) / NW;
    const int lo = blockIdx.x * chunk;
    const int hi = min(E, lo + chunk);
    for (int e = lo + tid; e < hi; e += 256)
        atomicAdd(&h[dst[e] >> TSH], 1);
    __syncthreads();
    for (int bk = tid; bk < NB; bk += 256)
        ghist[blockIdx.x * GH + bk] = h[bk];
}

// ---------------- K2: tile totals ----------------
__global__ __launch_bounds__(256) void btot_kernel(
    const int* __restrict__ ghist, int* __restrict__ btot)
{
    __shared__ int s[256];
    const int bk = blockIdx.x, t = threadIdx.x;
    s[t] = ghist[t * GH + bk];
    __syncthreads();
    for (int off = 128; off > 0; off >>= 1) {
        if (t < off) s[t] += s[t + off];
        __syncthreads();
    }
    if (t == 0) btot[bk] = s[0];
}

// ---------------- K3: serial scan of tile totals -> bbase ----------------
__global__ void bscan_kernel(const int* __restrict__ btot, int* __restrict__ bbase, int NB) {
    if (threadIdx.x == 0 && blockIdx.x == 0) {
        int run = 0;
        for (int i = 0; i < NB; i++) { bbase[i] = run; run += btot[i]; }
        bbase[NB] = run;
    }
}

// ---------------- K4: per-(tile, block) offsets ----------------
__global__ __launch_bounds__(256) void boff_kernel(
    const int* __restrict__ ghist, const int* __restrict__ bbase,
    int* __restrict__ goff)
{
    __shared__ int s[256];
    const int bk = blockIdx.x, t = threadIdx.x;
    const int v = ghist[t * GH + bk];
    s[t] = v;
    __syncthreads();
    for (int off = 1; off < 256; off <<= 1) {
        int u = (t >= off) ? s[t - off] : 0;
        __syncthreads();
        s[t] += u;
        __syncthreads();
    }
    goff[bk * 256 + t] = bbase[bk] + s[t] - v;   // exclusive
}

// ---------------- K5: partition edges into tile-grouped staging ----------------
__global__ __launch_bounds__(256) void part_kernel(
    const int* __restrict__ src, const int* __restrict__ dst,
    const int* __restrict__ goff, unsigned* __restrict__ staging, int E, int NB)
{
    __shared__ int cur[NBMAX];
    const int tid = threadIdx.x;
    const int blk = blockIdx.x;
    for (int bk = tid; bk < NB; bk += 256) cur[bk] = goff[bk * 256 + blk];
    __syncthreads();
    const int chunk = (E + NW - 1) / NW;
    const int lo = blk * chunk;
    const int hi = min(E, lo + chunk);
    for (int e = lo + tid; e < hi; e += 256) {
        int d = dst[e], s = src[e];
        int bk = d >> TSH;
        int p = atomicAdd(&cur[bk], 1);
        staging[p] = ((unsigned)(d & (TS - 1)) << 17) | (unsigned)s;
    }
}

// ---------------- K6: per-tile CSR build (rowptr slice + confined scatter) ----------------
__global__ __launch_bounds__(256) void build_kernel(
    const unsigned* __restrict__ staging, const int* __restrict__ bbase,
    int* __restrict__ rowptr, int* __restrict__ csr, int N)
{
    __shared__ int scnt[TS];
    __shared__ int sscan[TS];
    __shared__ int spos[TS];
    __shared__ int scur[TS];
    const int b = blockIdx.x, tid = threadIdx.x;
    if (tid < TS) { scnt[tid] = 0; scur[tid] = 0; }
    __syncthreads();
    const int seg0 = bbase[b], seg1 = bbase[b + 1];
    const int len = seg1 - seg0;
    const unsigned* st = staging + seg0;
    for (int i = tid; i < len; i += 256)
        atomicAdd(&scnt[(st[i] >> 17) & (TS - 1)], 1);
    __syncthreads();
    if (tid < TS) sscan[tid] = scnt[tid];
    __syncthreads();
    for (int off = 1; off < TS; off <<= 1) {
        int v = (tid < TS && tid >= off) ? sscan[tid - off] : 0;
        __syncthreads();
        if (tid < TS) sscan[tid] += v;
        __syncthreads();
    }
    const int node0 = b << TSH;
    if (tid < TS) {
        int excl = sscan[tid] - scnt[tid];
        spos[tid] = excl;
        int n = node0 + tid;
        if (n <= N) rowptr[n] = seg0 + excl;
    }
    __syncthreads();
    for (int i = tid; i < len; i += 256) {
        unsigned w = st[i];
        int dl = (w >> 17) & (TS - 1);
        int s = (int)(w & 0x1FFFFu);
        int p = atomicAdd(&scur[dl], 1);
        csr[seg0 + spos[dl] + p] = s;
    }
}

// ---------------- W prep: Wt[col][k] (gemm1) and Wt2[col][k] (final) ----------------
__global__ __launch_bounds__(256) void wprep_kernel(
    const float* __restrict__ W1l, const float* __restrict__ W1r,
    const float* __restrict__ W2l, const float* __restrict__ W2r,
    unsigned short* __restrict__ Wt, unsigned short* __restrict__ Wt2)
{
    const int tid = threadIdx.x;
    for (int i = 0; i < 64; i++) {
        int idx = i * 256 + tid;            // 0..16383
        int k = idx >> 7;
        int c = idx & 127;
        float v = (c < 64) ? W1l[k * 64 + c] : W1r[k * 64 + (c - 64)];
        Wt[c * 128 + k] = f2b(v);
    }
    // Wt2: 64 cols x 128 k. col<40 real, else 0. k<64 -> W2r[k][col], k>=64 -> W2l[k-64][col]
    for (int i = 0; i < 32; i++) {
        int idx = i * 256 + tid;            // 0..8191
        int c = idx >> 7;                   // 0..63
        int k = idx & 127;                  // 0..127
        float v = 0.f;
        if (c < NCLS) v = (k < 64) ? W2r[k * NCLS + c] : W2l[(k - 64) * NCLS + c];
        Wt2[c * 128 + k] = f2b(v);
    }
}

// ---------------- layer-1 MFMA GEMM: p1b = bf16(x@W1l), qb = bf16(x@W1r + b1) ----------------
__global__ __launch_bounds__(256) void gemm1_kernel(
    const float* __restrict__ x, const unsigned short* __restrict__ Wt,
    const float* __restrict__ b1,
    unsigned short* __restrict__ p1b, unsigned short* __restrict__ qb, int N)
{
    __shared__ alignas(16) unsigned short sW[128 * 136];
    const int tid = threadIdx.x;
    {
        const int4v* Wg = (const int4v*)Wt;
        #pragma unroll
        for (int i = 0; i < 8; i++) {
            int idx16 = i * 256 + tid;
            int c = idx16 >> 4;
            int k8 = idx16 & 15;
            int4v v = Wg[idx16];
            *(int4v*)&sW[c * 136 + k8 * 8] = v;
        }
    }
    __syncthreads();

    const int w = tid >> 6;
    const int lane = tid & 63;
    const int m = lane & 15;
    const int g = lane >> 4;

    const int node0 = blockIdx.x * 64;
    int arow = node0 + w * 16 + m;
    int arow_c = arow < N ? arow : 0;
    const float* xr = x + (size_t)arow_c * F_IN;

    f32x4 acc[8];
    #pragma unroll
    for (int c = 0; c < 8; c++) acc[c] = (f32x4){0.f, 0.f, 0.f, 0.f};

    #pragma unroll
    for (int ks = 0; ks < 4; ks++) {
        const int k0 = ks * 32 + g * 8;
        f32x4 xa = *(const f32x4*)(xr + k0);
        f32x4 xb = *(const f32x4*)(xr + k0 + 4);
        bf16x8 a;
        a[0] = (short)f2b(xa.x); a[1] = (short)f2b(xa.y);
        a[2] = (short)f2b(xa.z); a[3] = (short)f2b(xa.w);
        a[4] = (short)f2b(xb.x); a[5] = (short)f2b(xb.y);
        a[6] = (short)f2b(xb.z); a[7] = (short)f2b(xb.w);
        #pragma unroll
        for (int ct = 0; ct < 8; ct++) {
            bf16x8 b = *(const bf16x8*)&sW[(ct * 16 + m) * 136 + k0];
            acc[ct] = __builtin_amdgcn_mfma_f32_16x16x32_bf16(a, b, acc[ct], 0, 0, 0);
        }
    }

    float bias[4];
    #pragma unroll
    for (int ct = 4; ct < 8; ct++) bias[ct - 4] = b1[(ct - 4) * 16 + m];

    #pragma unroll
    for (int ct = 0; ct < 8; ct++) {
        const int col = ct * 16 + m;
        #pragma unroll
        for (int r = 0; r < 4; r++) {
            int nd = node0 + w * 16 + g * 4 + r;
            if (nd < N) {
                if (col < 64)
                    p1b[(size_t)nd * HID + col] = f2b(acc[ct][r]);
                else
                    qb[(size_t)nd * HID + (col - 64)] = f2b(acc[ct][r] + bias[ct - 4]);
            }
        }
    }
}

// ---------------- agg1: hb = bf16(relu(mean(p1b[nbrs]) + qb)) ----------------
__global__ __launch_bounds__(256) void agg1_kernel(
    const int* __restrict__ rowptr, const int* __restrict__ csr,
    const unsigned short* __restrict__ p1b, const unsigned short* __restrict__ qb,
    unsigned short* __restrict__ hb, int N)
{
    const int node = (blockIdx.x * 256 + threadIdx.x) >> 6;
    const int f = threadIdx.x & 63;
    if (node >= N) return;
    const int beg = rowptr[node];
    const int end = rowptr[node + 1];
    float s0 = 0.f, s1 = 0.f, s2 = 0.f, s3 = 0.f;
    float s4 = 0.f, s5 = 0.f, s6 = 0.f, s7 = 0.f;
    int j = beg;
    for (; j + 7 < end; j += 8) {
        int i0 = csr[j], i1 = csr[j+1], i2 = csr[j+2], i3 = csr[j+3];
        int i4 = csr[j+4], i5 = csr[j+5], i6 = csr[j+6], i7 = csr[j+7];
        s0 += b2f(p1b[(size_t)i0 * HID + f]);
        s1 += b2f(p1b[(size_t)i1 * HID + f]);
        s2 += b2f(p1b[(size_t)i2 * HID + f]);
        s3 += b2f(p1b[(size_t)i3 * HID + f]);
        s4 += b2f(p1b[(size_t)i4 * HID + f]);
        s5 += b2f(p1b[(size_t)i5 * HID + f]);
        s6 += b2f(p1b[(size_t)i6 * HID + f]);
        s7 += b2f(p1b[(size_t)i7 * HID + f]);
    }
    for (; j < end; j++) s0 += b2f(p1b[(size_t)csr[j] * HID + f]);
    float s = ((s0 + s1) + (s2 + s3)) + ((s4 + s5) + (s6 + s7));
    float dg = (float)(end - beg);
    dg = dg > 1.f ? dg : 1.f;
    float v = s / dg + b2f(qb[(size_t)node * HID + f]);
    v = v > 0.f ? v : 0.f;
    hb[(size_t)node * HID + f] = f2b(v);
}

// ---------------- agg2: agghb = bf16(mean(hb[nbrs])) ----------------
__global__ __launch_bounds__(256) void agg2_kernel(
    const int* __restrict__ rowptr, const int* __restrict__ csr,
    const unsigned short* __restrict__ hb, unsigned short* __restrict__ agghb, int N)
{
    const int node = (blockIdx.x * 256 + threadIdx.x) >> 6;
    const int f = threadIdx.x & 63;
    if (node >= N) return;
    const int beg = rowptr[node];
    const int end = rowptr[node + 1];
    float s0 = 0.f, s1 = 0.f, s2 = 0.f, s3 = 0.f;
    float s4 = 0.f, s5 = 0.f, s6 = 0.f, s7 = 0.f;
    int j = beg;
    for (; j + 7 < end; j += 8) {
        int i0 = csr[j], i1 = csr[j+1], i2 = csr[j+2], i3 = csr[j+3];
        int i4 = csr[j+4], i5 = csr[j+5], i6 = csr[j+6], i7 = csr[j+7];
        s0 += b2f(hb[(size_t)i0 * HID + f]);
        s1 += b2f(hb[(size_t)i1 * HID + f]);
        s2 += b2f(hb[(size_t)i2 * HID + f]);
        s3 += b2f(hb[(size_t)i3 * HID + f]);
        s4 += b2f(hb[(size_t)i4 * HID + f]);
        s5 += b2f(hb[(size_t)i5 * HID + f]);
        s6 += b2f(hb[(size_t)i6 * HID + f]);
        s7 += b2f(hb[(size_t)i7 * HID + f]);
    }
    for (; j < end; j++) s0 += b2f(hb[(size_t)csr[j] * HID + f]);
    float s = ((s0 + s1) + (s2 + s3)) + ((s4 + s5) + (s6 + s7));
    float dg = (float)(end - beg);
    dg = dg > 1.f ? dg : 1.f;
    agghb[(size_t)node * HID + f] = f2b(s / dg);
}

// ---------------- final MFMA: out = log_softmax([hb|agghb] @ Wt2 + b2) ----------------
// block: 64 nodes, 4 waves; wave = 16 nodes x 48 cols (3 MFMA col-tiles)
__global__ __launch_bounds__(256) void final_kernel(
    const unsigned short* __restrict__ hb, const unsigned short* __restrict__ agghb,
    const unsigned short* __restrict__ Wt2, const float* __restrict__ b2,
    float* __restrict__ out, int N)
{
    __shared__ alignas(16) unsigned short sW[64 * 136];   // 17.4 KB
    const int tid = threadIdx.x;
    {
        const int4v* Wg = (const int4v*)Wt2;
        #pragma unroll
        for (int i = 0; i < 4; i++) {
            int idx16 = i * 256 + tid;            // 0..1023
            int c = idx16 >> 4;                   // 0..63
            int k8 = idx16 & 15;
            int4v v = Wg[idx16];
            *(int4v*)&sW[c * 136 + k8 * 8] = v;
        }
    }
    __syncthreads();

    const int w = tid >> 6;
    const int lane = tid & 63;
    const int m = lane & 15;
    const int g = lane >> 4;

    const int node0 = blockIdx.x * 64;
    int arow = node0 + w * 16 + m;
    int arow_c = arow < N ? arow : 0;
    const unsigned short* hr = hb + (size_t)arow_c * HID;
    const unsigned short* ar = agghb + (size_t)arow_c * HID;

    f32x4 acc[3];
    #pragma unroll
    for (int c = 0; c < 3; c++) acc[c] = (f32x4){0.f, 0.f, 0.f, 0.f};

    #pragma unroll
    for (int ks = 0; ks < 4; ks++) {
        const int k0 = ks * 32 + g * 8;           // 0..120, never straddles 64
        bf16x8 a = (k0 < 64) ? *(const bf16x8*)(hr + k0)
                             : *(const bf16x8*)(ar + (k0 - 64));
        #pragma unroll
        for (int ct = 0; ct < 3; ct++) {
            bf16x8 b = *(const bf16x8*)&sW[(ct * 16 + m) * 136 + k0];
            acc[ct] = __builtin_amdgcn_mfma_f32_16x16x32_bf16(a, b, acc[ct], 0, 0, 0);
        }
    }

    // bias per col-tile (col = ct*16+m)
    float bias[3];
    #pragma unroll
    for (int ct = 0; ct < 3; ct++) {
        int col = ct * 16 + m;
        bias[ct] = (col < NCLS) ? b2[col] : 0.f;
    }
    const bool v2 = (m < 8);    // col 32+m < 40

    #pragma unroll
    for (int r = 0; r < 4; r++) {
        int nd = node0 + w * 16 + g * 4 + r;
        float l0 = acc[0][r] + bias[0];
        float l1 = acc[1][r] + bias[1];
        float l2 = acc[2][r] + bias[2];
        // row max over valid cols (lanes m=0..15 of this g-group hold the row)
        float mx = fmaxf(l0, l1);
        if (v2) mx = fmaxf(mx, l2);
        mx = fmaxf(mx, __shfl_xor(mx, 1));
        mx = fmaxf(mx, __shfl_xor(mx, 2));
        mx = fmaxf(mx, __shfl_xor(mx, 4));
        mx = fmaxf(mx, __shfl_xor(mx, 8));
        float s = __expf(l0 - mx) + __expf(l1 - mx) + (v2 ? __expf(l2 - mx) : 0.f);
        s += __shfl_xor(s, 1);
        s += __shfl_xor(s, 2);
        s += __shfl_xor(s, 4);
        s += __shfl_xor(s, 8);
        float lse = mx + __logf(s);
        if (nd < N) {
            float* orow = out + (size_t)nd * NCLS;
            orow[m] = l0 - lse;
            orow[16 + m] = l1 - lse;
            if (v2) orow[32 + m] = l2 - lse;
        }
    }
}

extern "C" void kernel_launch(void* const* d_in, const int* in_sizes, int n_in,
                              void* d_out, int out_size, void* d_ws, size_t ws_size,
                              hipStream_t stream) {
    const float* x   = (const float*)d_in[0];
    const int*   ei  = (const int*)d_in[1];
    const float* W1l = (const float*)d_in[2];
    const float* W1r = (const float*)d_in[3];
    const float* b1  = (const float*)d_in[4];
    const float* W2l = (const float*)d_in[5];
    const float* W2r = (const float*)d_in[6];
    const float* b2  = (const float*)d_in[7];

    const int N = in_sizes[0] / F_IN;
    const int E = in_sizes[1] / 2;
    const int* src = ei;
    const int* dst = ei + E;
    const int NB = (N + TS - 1) >> TSH;    // 782 for N=100000

    // ---- workspace layout (int elements) ----
    int* wsi = (int*)d_ws;
    size_t o = 0;
    int* rowptr = wsi + o;  o += (size_t)N + 64;            // N+1
    int* btot   = wsi + o;  o += 1024;
    int* bbase  = wsi + o;  o += 1024;                      // NB+1
    int* ghist  = wsi + o;  o += (size_t)NW * GH;           // [block][tile]
    int* goff   = wsi + o;  o += (size_t)NBMAX * NW;        // [tile][block]
    o = (o + 63) & ~(size_t)63;
    unsigned* staging = (unsigned*)(wsi + o);  o += E;      // tile-grouped packed edges
    int* csr    = wsi + o;  o += E;
    o = (o + 63) & ~(size_t)63;
    unsigned short* Wt  = (unsigned short*)(wsi + o);  o += 8192;            // 128x128 bf16
    unsigned short* Wt2 = (unsigned short*)(wsi + o);  o += 4096;            // 64x128 bf16
    unsigned short* p1b = (unsigned short*)(wsi + o);  o += (size_t)32 * N;  // 64N bf16 (reused as agghb)
    unsigned short* hb  = (unsigned short*)(wsi + o);  o += (size_t)32 * N;  // 64N bf16
    unsigned short* qb  = (unsigned short*)(wsi + o);  o += (size_t)32 * N;  // 64N bf16
    unsigned short* agghb = p1b;     // alias: p1b dead after agg1
    float* out  = (float*)d_out;

    hist_kernel <<<NW, 256, 0, stream>>>(dst, ghist, E, NB);
    btot_kernel <<<NB, 256, 0, stream>>>(ghist, btot);
    bscan_kernel<<<1, 64, 0, stream>>>(btot, bbase, NB);
    boff_kernel <<<NB, 256, 0, stream>>>(ghist, bbase, goff);
    part_kernel <<<NW, 256, 0, stream>>>(src, dst, goff, staging, E, NB);
    build_kernel<<<NB, 256, 0, stream>>>(staging, bbase, rowptr, csr, N);

    wprep_kernel<<<1, 256, 0, stream>>>(W1l, W1r, W2l, W2r, Wt, Wt2);
    gemm1_kernel<<<(N + 63) / 64, 256, 0, stream>>>(x, Wt, b1, p1b, qb, N);
    agg1_kernel<<<(N + 3) / 4, 256, 0, stream>>>(rowptr, csr, p1b, qb, hb, N);
    agg2_kernel<<<(N + 3) / 4, 256, 0, stream>>>(rowptr, csr, hb, agghb, N);
    final_kernel<<<(N + 63) / 64, 256, 0, stream>>>(hb, agghb, Wt2, b2, out, N);
}

// Round 10
// 222.691 us; speedup vs baseline: 7.1455x; 1.1770x over previous
//
#include <hip/hip_runtime.h>

#define F_IN 128
#define HID 64
#define NCLS 40

#define TSH 7              // tile shift
#define TS  128            // nodes per dst tile
#define NBMAX 800          // max tiles (N <= 102400)
#define GH 800             // ghist stride
#define NW 256             // writer blocks for hist/part

typedef __attribute__((ext_vector_type(8))) short bf16x8;
typedef __attribute__((ext_vector_type(8))) float f32x8;
typedef __attribute__((ext_vector_type(4))) float f32x4;
typedef __attribute__((ext_vector_type(4))) int int4v;

__device__ __forceinline__ unsigned short f2b(float f) {
    union { float f; unsigned int u; } v; v.f = f;
    unsigned int u = v.u + 0x7FFFu + ((v.u >> 16) & 1u);
    return (unsigned short)(u >> 16);
}
__device__ __forceinline__ float b2f(unsigned short b) {
    union { unsigned int u; float f; } v; v.u = ((unsigned int)b) << 16;
    return v.f;
}

// ---------------- K1: per-block histogram over dst tiles ----------------
__global__ __launch_bounds__(256) void hist_kernel(
    const int* __restrict__ dst, int* __restrict__ ghist, int E, int NB)
{
    __shared__ int h[NBMAX];
    const int tid = threadIdx.x;
    for (int i = tid; i < NBMAX; i += 256) h[i] = 0;
    __syncthreads();
    const int chunk = (E + NW - 1) / NW;
    const int lo = blockIdx.x * chunk;
    const int hi = min(E, lo + chunk);
    for (int e = lo + tid; e < hi; e += 256)
        atomicAdd(&h[dst[e] >> TSH], 1);
    __syncthreads();
    for (int bk = tid; bk < NB; bk += 256)
        ghist[blockIdx.x * GH + bk] = h[bk];
}

// ---------------- K2: tile totals ----------------
__global__ __launch_bounds__(256) void btot_kernel(
    const int* __restrict__ ghist, int* __restrict__ btot)
{
    __shared__ int s[256];
    const int bk = blockIdx.x, t = threadIdx.x;
    s[t] = ghist[t * GH + bk];
    __syncthreads();
    for (int off = 128; off > 0; off >>= 1) {
        if (t < off) s[t] += s[t + off];
        __syncthreads();
    }
    if (t == 0) btot[bk] = s[0];
}

// ---------------- K3: serial scan of tile totals -> bbase ----------------
__global__ void bscan_kernel(const int* __restrict__ btot, int* __restrict__ bbase, int NB) {
    if (threadIdx.x == 0 && blockIdx.x == 0) {
        int run = 0;
        for (int i = 0; i < NB; i++) { bbase[i] = run; run += btot[i]; }
        bbase[NB] = run;
    }
}

// ---------------- K4: per-(tile, block) offsets ----------------
__global__ __launch_bounds__(256) void boff_kernel(
    const int* __restrict__ ghist, const int* __restrict__ bbase,
    int* __restrict__ goff)
{
    __shared__ int s[256];
    const int bk = blockIdx.x, t = threadIdx.x;
    const int v = ghist[t * GH + bk];
    s[t] = v;
    __syncthreads();
    for (int off = 1; off < 256; off <<= 1) {
        int u = (t >= off) ? s[t - off] : 0;
        __syncthreads();
        s[t] += u;
        __syncthreads();
    }
    goff[bk * 256 + t] = bbase[bk] + s[t] - v;   // exclusive
}

// ---------------- K5: partition edges into tile-grouped staging ----------------
__global__ __launch_bounds__(256) void part_kernel(
    const int* __restrict__ src, const int* __restrict__ dst,
    const int* __restrict__ goff, unsigned* __restrict__ staging, int E, int NB)
{
    __shared__ int cur[NBMAX];
    const int tid = threadIdx.x;
    const int blk = blockIdx.x;
    for (int bk = tid; bk < NB; bk += 256) cur[bk] = goff[bk * 256 + blk];
    __syncthreads();
    const int chunk = (E + NW - 1) / NW;
    const int lo = blk * chunk;
    const int hi = min(E, lo + chunk);
    for (int e = lo + tid; e < hi; e += 256) {
        int d = dst[e], s = src[e];
        int bk = d >> TSH;
        int p = atomicAdd(&cur[bk], 1);
        staging[p] = ((unsigned)(d & (TS - 1)) << 17) | (unsigned)s;
    }
}

// ---------------- K6: per-tile CSR build (rowptr slice + confined scatter) ----------------
__global__ __launch_bounds__(256) void build_kernel(
    const unsigned* __restrict__ staging, const int* __restrict__ bbase,
    int* __restrict__ rowptr, int* __restrict__ csr, int N)
{
    __shared__ int scnt[TS];
    __shared__ int sscan[TS];
    __shared__ int spos[TS];
    __shared__ int scur[TS];
    const int b = blockIdx.x, tid = threadIdx.x;
    if (tid < TS) { scnt[tid] = 0; scur[tid] = 0; }
    __syncthreads();
    const int seg0 = bbase[b], seg1 = bbase[b + 1];
    const int len = seg1 - seg0;
    const unsigned* st = staging + seg0;
    for (int i = tid; i < len; i += 256)
        atomicAdd(&scnt[(st[i] >> 17) & (TS - 1)], 1);
    __syncthreads();
    if (tid < TS) sscan[tid] = scnt[tid];
    __syncthreads();
    for (int off = 1; off < TS; off <<= 1) {
        int v = (tid < TS && tid >= off) ? sscan[tid - off] : 0;
        __syncthreads();
        if (tid < TS) sscan[tid] += v;
        __syncthreads();
    }
    const int node0 = b << TSH;
    if (tid < TS) {
        int excl = sscan[tid] - scnt[tid];
        spos[tid] = excl;
        int n = node0 + tid;
        if (n <= N) rowptr[n] = seg0 + excl;
    }
    __syncthreads();
    for (int i = tid; i < len; i += 256) {
        unsigned w = st[i];
        int dl = (w >> 17) & (TS - 1);
        int s = (int)(w & 0x1FFFFu);
        int p = atomicAdd(&scur[dl], 1);
        csr[seg0 + spos[dl] + p] = s;
    }
}

// ---------------- W prep: Wt[col][k] (gemm1) and Wt2[col][k] (final) ----------------
__global__ __launch_bounds__(256) void wprep_kernel(
    const float* __restrict__ W1l, const float* __restrict__ W1r,
    const float* __restrict__ W2l, const float* __restrict__ W2r,
    unsigned short* __restrict__ Wt, unsigned short* __restrict__ Wt2)
{
    const int tid = threadIdx.x;
    for (int i = 0; i < 64; i++) {
        int idx = i * 256 + tid;            // 0..16383
        int k = idx >> 7;
        int c = idx & 127;
        float v = (c < 64) ? W1l[k * 64 + c] : W1r[k * 64 + (c - 64)];
        Wt[c * 128 + k] = f2b(v);
    }
    // Wt2: 64 cols x 128 k. col<40 real, else 0. k<64 -> W2r[k][col], k>=64 -> W2l[k-64][col]
    for (int i = 0; i < 32; i++) {
        int idx = i * 256 + tid;            // 0..8191
        int c = idx >> 7;                   // 0..63
        int k = idx & 127;                  // 0..127
        float v = 0.f;
        if (c < NCLS) v = (k < 64) ? W2r[k * NCLS + c] : W2l[(k - 64) * NCLS + c];
        Wt2[c * 128 + k] = f2b(v);
    }
}

// ---------------- layer-1 MFMA GEMM: p1b = bf16(x@W1l), qb = bf16(x@W1r + b1) ----------------
__global__ __launch_bounds__(256) void gemm1_kernel(
    const float* __restrict__ x, const unsigned short* __restrict__ Wt,
    const float* __restrict__ b1,
    unsigned short* __restrict__ p1b, unsigned short* __restrict__ qb, int N)
{
    __shared__ alignas(16) unsigned short sW[128 * 136];
    const int tid = threadIdx.x;
    {
        const int4v* Wg = (const int4v*)Wt;
        #pragma unroll
        for (int i = 0; i < 8; i++) {
            int idx16 = i * 256 + tid;
            int c = idx16 >> 4;
            int k8 = idx16 & 15;
            int4v v = Wg[idx16];
            *(int4v*)&sW[c * 136 + k8 * 8] = v;
        }
    }
    __syncthreads();

    const int w = tid >> 6;
    const int lane = tid & 63;
    const int m = lane & 15;
    const int g = lane >> 4;

    const int node0 = blockIdx.x * 64;
    int arow = node0 + w * 16 + m;
    int arow_c = arow < N ? arow : 0;
    const float* xr = x + (size_t)arow_c * F_IN;

    f32x4 acc[8];
    #pragma unroll
    for (int c = 0; c < 8; c++) acc[c] = (f32x4){0.f, 0.f, 0.f, 0.f};

    #pragma unroll
    for (int ks = 0; ks < 4; ks++) {
        const int k0 = ks * 32 + g * 8;
        f32x4 xa = *(const f32x4*)(xr + k0);
        f32x4 xb = *(const f32x4*)(xr + k0 + 4);
        bf16x8 a;
        a[0] = (short)f2b(xa.x); a[1] = (short)f2b(xa.y);
        a[2] = (short)f2b(xa.z); a[3] = (short)f2b(xa.w);
        a[4] = (short)f2b(xb.x); a[5] = (short)f2b(xb.y);
        a[6] = (short)f2b(xb.z); a[7] = (short)f2b(xb.w);
        #pragma unroll
        for (int ct = 0; ct < 8; ct++) {
            bf16x8 b = *(const bf16x8*)&sW[(ct * 16 + m) * 136 + k0];
            acc[ct] = __builtin_amdgcn_mfma_f32_16x16x32_bf16(a, b, acc[ct], 0, 0, 0);
        }
    }

    float bias[4];
    #pragma unroll
    for (int ct = 4; ct < 8; ct++) bias[ct - 4] = b1[(ct - 4) * 16 + m];

    #pragma unroll
    for (int ct = 0; ct < 8; ct++) {
        const int col = ct * 16 + m;
        #pragma unroll
        for (int r = 0; r < 4; r++) {
            int nd = node0 + w * 16 + g * 4 + r;
            if (nd < N) {
                if (col < 64)
                    p1b[(size_t)nd * HID + col] = f2b(acc[ct][r]);
                else
                    qb[(size_t)nd * HID + (col - 64)] = f2b(acc[ct][r] + bias[ct - 4]);
            }
        }
    }
}

// ---------------- agg1: hb = bf16(relu(mean(p1b[nbrs]) + qb)) ----------------
// wave per node; slot = lane>>3 (8 edges in flight), fg = lane&7 (8 feats, 16B loads)
__global__ __launch_bounds__(256) void agg1_kernel(
    const int* __restrict__ rowptr, const int* __restrict__ csr,
    const unsigned short* __restrict__ p1b, const unsigned short* __restrict__ qb,
    unsigned short* __restrict__ hb, int N)
{
    const int node = (blockIdx.x * 256 + threadIdx.x) >> 6;
    if (node >= N) return;
    const int lane = threadIdx.x & 63;
    const int slot = lane >> 3;
    const int fg   = lane & 7;
    const int beg = rowptr[node];
    const int end = rowptr[node + 1];

    f32x8 acc = (f32x8){0.f,0.f,0.f,0.f,0.f,0.f,0.f,0.f};
    for (int j = beg + slot; j < end; j += 8) {
        int s = csr[j];                                   // 8 lanes/slot share -> broadcast
        bf16x8 v = *(const bf16x8*)(p1b + (size_t)s * HID + fg * 8);
        #pragma unroll
        for (int k = 0; k < 8; k++) acc[k] += b2f((unsigned short)v[k]);
    }
    // cross-slot reduce (slots differ by lane bits 3..5)
    #pragma unroll
    for (int k = 0; k < 8; k++) {
        float a = acc[k];
        a += __shfl_xor(a, 8);
        a += __shfl_xor(a, 16);
        a += __shfl_xor(a, 32);
        acc[k] = a;
    }
    if (slot == 0) {
        float dg = (float)(end - beg);
        dg = dg > 1.f ? dg : 1.f;
        float inv = 1.f / dg;
        bf16x8 q = *(const bf16x8*)(qb + (size_t)node * HID + fg * 8);
        bf16x8 ov;
        #pragma unroll
        for (int k = 0; k < 8; k++) {
            float v = acc[k] * inv + b2f((unsigned short)q[k]);
            v = v > 0.f ? v : 0.f;
            ov[k] = (short)f2b(v);
        }
        *(bf16x8*)(hb + (size_t)node * HID + fg * 8) = ov;
    }
}

// ---------------- agg2: agghb = bf16(mean(hb[nbrs])) ----------------
__global__ __launch_bounds__(256) void agg2_kernel(
    const int* __restrict__ rowptr, const int* __restrict__ csr,
    const unsigned short* __restrict__ hb, unsigned short* __restrict__ agghb, int N)
{
    const int node = (blockIdx.x * 256 + threadIdx.x) >> 6;
    if (node >= N) return;
    const int lane = threadIdx.x & 63;
    const int slot = lane >> 3;
    const int fg   = lane & 7;
    const int beg = rowptr[node];
    const int end = rowptr[node + 1];

    f32x8 acc = (f32x8){0.f,0.f,0.f,0.f,0.f,0.f,0.f,0.f};
    for (int j = beg + slot; j < end; j += 8) {
        int s = csr[j];
        bf16x8 v = *(const bf16x8*)(hb + (size_t)s * HID + fg * 8);
        #pragma unroll
        for (int k = 0; k < 8; k++) acc[k] += b2f((unsigned short)v[k]);
    }
    #pragma unroll
    for (int k = 0; k < 8; k++) {
        float a = acc[k];
        a += __shfl_xor(a, 8);
        a += __shfl_xor(a, 16);
        a += __shfl_xor(a, 32);
        acc[k] = a;
    }
    if (slot == 0) {
        float dg = (float)(end - beg);
        dg = dg > 1.f ? dg : 1.f;
        float inv = 1.f / dg;
        bf16x8 ov;
        #pragma unroll
        for (int k = 0; k < 8; k++) ov[k] = (short)f2b(acc[k] * inv);
        *(bf16x8*)(agghb + (size_t)node * HID + fg * 8) = ov;
    }
}

// ---------------- final MFMA: out = log_softmax([hb|agghb] @ Wt2 + b2) ----------------
__global__ __launch_bounds__(256) void final_kernel(
    const unsigned short* __restrict__ hb, const unsigned short* __restrict__ agghb,
    const unsigned short* __restrict__ Wt2, const float* __restrict__ b2,
    float* __restrict__ out, int N)
{
    __shared__ alignas(16) unsigned short sW[64 * 136];   // 17.4 KB
    const int tid = threadIdx.x;
    {
        const int4v* Wg = (const int4v*)Wt2;
        #pragma unroll
        for (int i = 0; i < 4; i++) {
            int idx16 = i * 256 + tid;            // 0..1023
            int c = idx16 >> 4;
            int k8 = idx16 & 15;
            int4v v = Wg[idx16];
            *(int4v*)&sW[c * 136 + k8 * 8] = v;
        }
    }
    __syncthreads();

    const int w = tid >> 6;
    const int lane = tid & 63;
    const int m = lane & 15;
    const int g = lane >> 4;

    const int node0 = blockIdx.x * 64;
    int arow = node0 + w * 16 + m;
    int arow_c = arow < N ? arow : 0;
    const unsigned short* hr = hb + (size_t)arow_c * HID;
    const unsigned short* ar = agghb + (size_t)arow_c * HID;

    f32x4 acc[3];
    #pragma unroll
    for (int c = 0; c < 3; c++) acc[c] = (f32x4){0.f, 0.f, 0.f, 0.f};

    #pragma unroll
    for (int ks = 0; ks < 4; ks++) {
        const int k0 = ks * 32 + g * 8;           // never straddles 64
        bf16x8 a = (k0 < 64) ? *(const bf16x8*)(hr + k0)
                             : *(const bf16x8*)(ar + (k0 - 64));
        #pragma unroll
        for (int ct = 0; ct < 3; ct++) {
            bf16x8 b = *(const bf16x8*)&sW[(ct * 16 + m) * 136 + k0];
            acc[ct] = __builtin_amdgcn_mfma_f32_16x16x32_bf16(a, b, acc[ct], 0, 0, 0);
        }
    }

    float bias[3];
    #pragma unroll
    for (int ct = 0; ct < 3; ct++) {
        int col = ct * 16 + m;
        bias[ct] = (col < NCLS) ? b2[col] : 0.f;
    }
    const bool v2 = (m < 8);

    #pragma unroll
    for (int r = 0; r < 4; r++) {
        int nd = node0 + w * 16 + g * 4 + r;
        float l0 = acc[0][r] + bias[0];
        float l1 = acc[1][r] + bias[1];
        float l2 = acc[2][r] + bias[2];
        float mx = fmaxf(l0, l1);
        if (v2) mx = fmaxf(mx, l2);
        mx = fmaxf(mx, __shfl_xor(mx, 1));
        mx = fmaxf(mx, __shfl_xor(mx, 2));
        mx = fmaxf(mx, __shfl_xor(mx, 4));
        mx = fmaxf(mx, __shfl_xor(mx, 8));
        float s = __expf(l0 - mx) + __expf(l1 - mx) + (v2 ? __expf(l2 - mx) : 0.f);
        s += __shfl_xor(s, 1);
        s += __shfl_xor(s, 2);
        s += __shfl_xor(s, 4);
        s += __shfl_xor(s, 8);
        float lse = mx + __logf(s);
        if (nd < N) {
            float* orow = out + (size_t)nd * NCLS;
            orow[m] = l0 - lse;
            orow[16 + m] = l1 - lse;
            if (v2) orow[32 + m] = l2 - lse;
        }
    }
}

extern "C" void kernel_launch(void* const* d_in, const int* in_sizes, int n_in,
                              void* d_out, int out_size, void* d_ws, size_t ws_size,
                              hipStream_t stream) {
    const float* x   = (const float*)d_in[0];
    const int*   ei  = (const int*)d_in[1];
    const float* W1l = (const float*)d_in[2];
    const float* W1r = (const float*)d_in[3];
    const float* b1  = (const float*)d_in[4];
    const float* W2l = (const float*)d_in[5];
    const float* W2r = (const float*)d_in[6];
    const float* b2  = (const float*)d_in[7];

    const int N = in_sizes[0] / F_IN;
    const int E = in_sizes[1] / 2;
    const int* src = ei;
    const int* dst = ei + E;
    const int NB = (N + TS - 1) >> TSH;    // 782 for N=100000

    // ---- workspace layout (int elements) ----
    int* wsi = (int*)d_ws;
    size_t o = 0;
    int* rowptr = wsi + o;  o += (size_t)N + 64;            // N+1
    int* btot   = wsi + o;  o += 1024;
    int* bbase  = wsi + o;  o += 1024;                      // NB+1
    int* ghist  = wsi + o;  o += (size_t)NW * GH;           // [block][tile]
    int* goff   = wsi + o;  o += (size_t)NBMAX * NW;        // [tile][block]
    o = (o + 63) & ~(size_t)63;
    unsigned* staging = (unsigned*)(wsi + o);  o += E;      // tile-grouped packed edges
    int* csr    = wsi + o;  o += E;
    o = (o + 63) & ~(size_t)63;
    unsigned short* Wt  = (unsigned short*)(wsi + o);  o += 8192;            // 128x128 bf16
    unsigned short* Wt2 = (unsigned short*)(wsi + o);  o += 4096;            // 64x128 bf16
    unsigned short* p1b = (unsigned short*)(wsi + o);  o += (size_t)32 * N;  // 64N bf16 (reused as agghb)
    unsigned short* hb  = (unsigned short*)(wsi + o);  o += (size_t)32 * N;  // 64N bf16
    unsigned short* qb  = (unsigned short*)(wsi + o);  o += (size_t)32 * N;  // 64N bf16
    unsigned short* agghb = p1b;     // alias: p1b dead after agg1
    float* out  = (float*)d_out;

    hist_kernel <<<NW, 256, 0, stream>>>(dst, ghist, E, NB);
    btot_kernel <<<NB, 256, 0, stream>>>(ghist, btot);
    bscan_kernel<<<1, 64, 0, stream>>>(btot, bbase, NB);
    boff_kernel <<<NB, 256, 0, stream>>>(ghist, bbase, goff);
    part_kernel <<<NW, 256, 0, stream>>>(src, dst, goff, staging, E, NB);
    build_kernel<<<NB, 256, 0, stream>>>(staging, bbase, rowptr, csr, N);

    wprep_kernel<<<1, 256, 0, stream>>>(W1l, W1r, W2l, W2r, Wt, Wt2);
    gemm1_kernel<<<(N + 63) / 64, 256, 0, stream>>>(x, Wt, b1, p1b, qb, N);
    agg1_kernel<<<(N + 3) / 4, 256, 0, stream>>>(rowptr, csr, p1b, qb, hb, N);
    agg2_kernel<<<(N + 3) / 4, 256, 0, stream>>>(rowptr, csr, hb, agghb, N);
    final_kernel<<<(N + 63) / 64, 256, 0, stream>>>(hb, agghb, Wt2, b2, out, N);
}

// Round 11
// 212.439 us; speedup vs baseline: 7.4903x; 1.0483x over previous
//
#include <hip/hip_runtime.h>

#define F_IN 128
#define HID 64
#define NCLS 40

#define TSH 7              // tile shift
#define TS  128            // nodes per dst tile
#define NBMAX 800          // max tiles (N <= 102400)
#define GH 800             // ghist stride
#define NW 256             // writer blocks for hist/part

typedef __attribute__((ext_vector_type(8))) short bf16x8;
typedef __attribute__((ext_vector_type(8))) float f32x8;
typedef __attribute__((ext_vector_type(4))) float f32x4;
typedef __attribute__((ext_vector_type(4))) int int4v;

__device__ __forceinline__ unsigned short f2b(float f) {
    union { float f; unsigned int u; } v; v.f = f;
    unsigned int u = v.u + 0x7FFFu + ((v.u >> 16) & 1u);
    return (unsigned short)(u >> 16);
}
__device__ __forceinline__ float b2f(unsigned short b) {
    union { unsigned int u; float f; } v; v.u = ((unsigned int)b) << 16;
    return v.f;
}

// ---------------- K1: per-block histogram over dst tiles (int4 loads) ----------------
__global__ __launch_bounds__(256) void hist_kernel(
    const int* __restrict__ dst, int* __restrict__ ghist, int E, int NB)
{
    __shared__ int h[NBMAX];
    const int tid = threadIdx.x;
    for (int i = tid; i < NBMAX; i += 256) h[i] = 0;
    __syncthreads();
    int chunk = (E + NW - 1) / NW;
    chunk = (chunk + 3) & ~3;
    const int lo = blockIdx.x * chunk;
    const int hi = min(E, lo + chunk);
    for (int e = lo + tid * 4; e + 3 < hi; e += 1024) {
        int4v d4 = *(const int4v*)(dst + e);
        atomicAdd(&h[d4.x >> TSH], 1);
        atomicAdd(&h[d4.y >> TSH], 1);
        atomicAdd(&h[d4.z >> TSH], 1);
        atomicAdd(&h[d4.w >> TSH], 1);
    }
    // tail (hi not multiple of 4 only in last chunk)
    {
        int tb = hi & ~3;
        if (tb < hi) {
            for (int e = tb + tid; e < hi; e += 256)
                atomicAdd(&h[dst[e] >> TSH], 1);
        }
    }
    __syncthreads();
    for (int bk = tid; bk < NB; bk += 256)
        ghist[blockIdx.x * GH + bk] = h[bk];
}

// ---------------- K2: tile totals ----------------
__global__ __launch_bounds__(256) void btot_kernel(
    const int* __restrict__ ghist, int* __restrict__ btot)
{
    __shared__ int s[256];
    const int bk = blockIdx.x, t = threadIdx.x;
    s[t] = ghist[t * GH + bk];
    __syncthreads();
    for (int off = 128; off > 0; off >>= 1) {
        if (t < off) s[t] += s[t + off];
        __syncthreads();
    }
    if (t == 0) btot[bk] = s[0];
}

// ---------------- K3: serial scan of tile totals -> bbase ----------------
__global__ void bscan_kernel(const int* __restrict__ btot, int* __restrict__ bbase, int NB) {
    if (threadIdx.x == 0 && blockIdx.x == 0) {
        int run = 0;
        for (int i = 0; i < NB; i++) { bbase[i] = run; run += btot[i]; }
        bbase[NB] = run;
    }
}

// ---------------- K4: per-(tile, block) offsets ----------------
__global__ __launch_bounds__(256) void boff_kernel(
    const int* __restrict__ ghist, const int* __restrict__ bbase,
    int* __restrict__ goff)
{
    __shared__ int s[256];
    const int bk = blockIdx.x, t = threadIdx.x;
    const int v = ghist[t * GH + bk];
    s[t] = v;
    __syncthreads();
    for (int off = 1; off < 256; off <<= 1) {
        int u = (t >= off) ? s[t - off] : 0;
        __syncthreads();
        s[t] += u;
        __syncthreads();
    }
    goff[bk * 256 + t] = bbase[bk] + s[t] - v;   // exclusive
}

// ---------------- K5: partition edges into tile-grouped staging (int4 loads) ----------------
__global__ __launch_bounds__(256) void part_kernel(
    const int* __restrict__ src, const int* __restrict__ dst,
    const int* __restrict__ goff, unsigned* __restrict__ staging, int E, int NB)
{
    __shared__ int cur[NBMAX];
    const int tid = threadIdx.x;
    const int blk = blockIdx.x;
    for (int bk = tid; bk < NB; bk += 256) cur[bk] = goff[bk * 256 + blk];
    __syncthreads();
    int chunk = (E + NW - 1) / NW;
    chunk = (chunk + 3) & ~3;
    const int lo = blk * chunk;
    const int hi = min(E, lo + chunk);
    for (int e = lo + tid * 4; e + 3 < hi; e += 1024) {
        int4v d4 = *(const int4v*)(dst + e);
        int4v s4 = *(const int4v*)(src + e);
        int d[4] = {d4.x, d4.y, d4.z, d4.w};
        int s[4] = {s4.x, s4.y, s4.z, s4.w};
        #pragma unroll
        for (int k = 0; k < 4; k++) {
            int bk = d[k] >> TSH;
            int p = atomicAdd(&cur[bk], 1);
            staging[p] = ((unsigned)(d[k] & (TS - 1)) << 17) | (unsigned)s[k];
        }
    }
    {
        int tb = hi & ~3;
        if (tb < hi) {
            for (int e = tb + tid; e < hi; e += 256) {
                int d = dst[e], s = src[e];
                int bk = d >> TSH;
                int p = atomicAdd(&cur[bk], 1);
                staging[p] = ((unsigned)(d & (TS - 1)) << 17) | (unsigned)s;
            }
        }
    }
}

// ---------------- K6: per-tile CSR build (rowptr slice + confined scatter) ----------------
__global__ __launch_bounds__(256) void build_kernel(
    const unsigned* __restrict__ staging, const int* __restrict__ bbase,
    int* __restrict__ rowptr, int* __restrict__ csr, int N)
{
    __shared__ int scnt[TS];
    __shared__ int sscan[TS];
    __shared__ int spos[TS];
    __shared__ int scur[TS];
    const int b = blockIdx.x, tid = threadIdx.x;
    if (tid < TS) { scnt[tid] = 0; scur[tid] = 0; }
    __syncthreads();
    const int seg0 = bbase[b], seg1 = bbase[b + 1];
    const int len = seg1 - seg0;
    const unsigned* st = staging + seg0;
    for (int i = tid; i < len; i += 256)
        atomicAdd(&scnt[(st[i] >> 17) & (TS - 1)], 1);
    __syncthreads();
    if (tid < TS) sscan[tid] = scnt[tid];
    __syncthreads();
    for (int off = 1; off < TS; off <<= 1) {
        int v = (tid < TS && tid >= off) ? sscan[tid - off] : 0;
        __syncthreads();
        if (tid < TS) sscan[tid] += v;
        __syncthreads();
    }
    const int node0 = b << TSH;
    if (tid < TS) {
        int excl = sscan[tid] - scnt[tid];
        spos[tid] = excl;
        int n = node0 + tid;
        if (n <= N) rowptr[n] = seg0 + excl;
    }
    __syncthreads();
    for (int i = tid; i < len; i += 256) {
        unsigned w = st[i];
        int dl = (w >> 17) & (TS - 1);
        int s = (int)(w & 0x1FFFFu);
        int p = atomicAdd(&scur[dl], 1);
        csr[seg0 + spos[dl] + p] = s;
    }
}

// ---------------- W prep: Wt[col][k] (gemm1) and Wt2[col][k] (final) ----------------
__global__ __launch_bounds__(256) void wprep_kernel(
    const float* __restrict__ W1l, const float* __restrict__ W1r,
    const float* __restrict__ W2l, const float* __restrict__ W2r,
    unsigned short* __restrict__ Wt, unsigned short* __restrict__ Wt2)
{
    const int tid = threadIdx.x;
    for (int i = 0; i < 64; i++) {
        int idx = i * 256 + tid;            // 0..16383
        int k = idx >> 7;
        int c = idx & 127;
        float v = (c < 64) ? W1l[k * 64 + c] : W1r[k * 64 + (c - 64)];
        Wt[c * 128 + k] = f2b(v);
    }
    // Wt2: 64 cols x 128 k. col<40 real, else 0. k<64 -> W2r[k][col], k>=64 -> W2l[k-64][col]
    for (int i = 0; i < 32; i++) {
        int idx = i * 256 + tid;            // 0..8191
        int c = idx >> 7;                   // 0..63
        int k = idx & 127;                  // 0..127
        float v = 0.f;
        if (c < NCLS) v = (k < 64) ? W2r[k * NCLS + c] : W2l[(k - 64) * NCLS + c];
        Wt2[c * 128 + k] = f2b(v);
    }
}

// ---------------- layer-1 MFMA GEMM: p1b = bf16(x@W1l), qb = bf16(x@W1r + b1) ----------------
__global__ __launch_bounds__(256) void gemm1_kernel(
    const float* __restrict__ x, const unsigned short* __restrict__ Wt,
    const float* __restrict__ b1,
    unsigned short* __restrict__ p1b, unsigned short* __restrict__ qb, int N)
{
    __shared__ alignas(16) unsigned short sW[128 * 136];
    const int tid = threadIdx.x;
    {
        const int4v* Wg = (const int4v*)Wt;
        #pragma unroll
        for (int i = 0; i < 8; i++) {
            int idx16 = i * 256 + tid;
            int c = idx16 >> 4;
            int k8 = idx16 & 15;
            int4v v = Wg[idx16];
            *(int4v*)&sW[c * 136 + k8 * 8] = v;
        }
    }
    __syncthreads();

    const int w = tid >> 6;
    const int lane = tid & 63;
    const int m = lane & 15;
    const int g = lane >> 4;

    const int node0 = blockIdx.x * 64;
    int arow = node0 + w * 16 + m;
    int arow_c = arow < N ? arow : 0;
    const float* xr = x + (size_t)arow_c * F_IN;

    f32x4 acc[8];
    #pragma unroll
    for (int c = 0; c < 8; c++) acc[c] = (f32x4){0.f, 0.f, 0.f, 0.f};

    #pragma unroll
    for (int ks = 0; ks < 4; ks++) {
        const int k0 = ks * 32 + g * 8;
        f32x4 xa = *(const f32x4*)(xr + k0);
        f32x4 xb = *(const f32x4*)(xr + k0 + 4);
        bf16x8 a;
        a[0] = (short)f2b(xa.x); a[1] = (short)f2b(xa.y);
        a[2] = (short)f2b(xa.z); a[3] = (short)f2b(xa.w);
        a[4] = (short)f2b(xb.x); a[5] = (short)f2b(xb.y);
        a[6] = (short)f2b(xb.z); a[7] = (short)f2b(xb.w);
        #pragma unroll
        for (int ct = 0; ct < 8; ct++) {
            bf16x8 b = *(const bf16x8*)&sW[(ct * 16 + m) * 136 + k0];
            acc[ct] = __builtin_amdgcn_mfma_f32_16x16x32_bf16(a, b, acc[ct], 0, 0, 0);
        }
    }

    float bias[4];
    #pragma unroll
    for (int ct = 4; ct < 8; ct++) bias[ct - 4] = b1[(ct - 4) * 16 + m];

    #pragma unroll
    for (int ct = 0; ct < 8; ct++) {
        const int col = ct * 16 + m;
        #pragma unroll
        for (int r = 0; r < 4; r++) {
            int nd = node0 + w * 16 + g * 4 + r;
            if (nd < N) {
                if (col < 64)
                    p1b[(size_t)nd * HID + col] = f2b(acc[ct][r]);
                else
                    qb[(size_t)nd * HID + (col - 64)] = f2b(acc[ct][r] + bias[ct - 4]);
            }
        }
    }
}

// ---------------- agg1: hb = bf16(relu(mean(p1b[nbrs]) + qb)) ----------------
// wave per node; slot = lane>>3 (8 slots), fg = lane&7 (16B loads); 2 rows in flight per slot
__global__ __launch_bounds__(256) void agg1_kernel(
    const int* __restrict__ rowptr, const int* __restrict__ csr,
    const unsigned short* __restrict__ p1b, const unsigned short* __restrict__ qb,
    unsigned short* __restrict__ hb, int N)
{
    const int node = (blockIdx.x * 256 + threadIdx.x) >> 6;
    if (node >= N) return;
    const int lane = threadIdx.x & 63;
    const int slot = lane >> 3;
    const int fg   = lane & 7;
    const int beg = rowptr[node];
    const int end = rowptr[node + 1];

    f32x8 acc0 = (f32x8){0.f,0.f,0.f,0.f,0.f,0.f,0.f,0.f};
    f32x8 acc1 = (f32x8){0.f,0.f,0.f,0.f,0.f,0.f,0.f,0.f};
    int j = beg + slot;
    for (; j + 8 < end; j += 16) {
        int s0 = csr[j];
        int s1 = csr[j + 8];
        bf16x8 v0 = *(const bf16x8*)(p1b + (size_t)s0 * HID + fg * 8);
        bf16x8 v1 = *(const bf16x8*)(p1b + (size_t)s1 * HID + fg * 8);
        #pragma unroll
        for (int k = 0; k < 8; k++) acc0[k] += b2f((unsigned short)v0[k]);
        #pragma unroll
        for (int k = 0; k < 8; k++) acc1[k] += b2f((unsigned short)v1[k]);
    }
    if (j < end) {
        int s0 = csr[j];
        bf16x8 v0 = *(const bf16x8*)(p1b + (size_t)s0 * HID + fg * 8);
        #pragma unroll
        for (int k = 0; k < 8; k++) acc0[k] += b2f((unsigned short)v0[k]);
    }
    #pragma unroll
    for (int k = 0; k < 8; k++) {
        float a = acc0[k] + acc1[k];
        a += __shfl_xor(a, 8);
        a += __shfl_xor(a, 16);
        a += __shfl_xor(a, 32);
        acc0[k] = a;
    }
    if (slot == 0) {
        float dg = (float)(end - beg);
        dg = dg > 1.f ? dg : 1.f;
        float inv = 1.f / dg;
        bf16x8 q = *(const bf16x8*)(qb + (size_t)node * HID + fg * 8);
        bf16x8 ov;
        #pragma unroll
        for (int k = 0; k < 8; k++) {
            float v = acc0[k] * inv + b2f((unsigned short)q[k]);
            v = v > 0.f ? v : 0.f;
            ov[k] = (short)f2b(v);
        }
        *(bf16x8*)(hb + (size_t)node * HID + fg * 8) = ov;
    }
}

// ---------------- agg2: agghb = bf16(mean(hb[nbrs])) ----------------
__global__ __launch_bounds__(256) void agg2_kernel(
    const int* __restrict__ rowptr, const int* __restrict__ csr,
    const unsigned short* __restrict__ hb, unsigned short* __restrict__ agghb, int N)
{
    const int node = (blockIdx.x * 256 + threadIdx.x) >> 6;
    if (node >= N) return;
    const int lane = threadIdx.x & 63;
    const int slot = lane >> 3;
    const int fg   = lane & 7;
    const int beg = rowptr[node];
    const int end = rowptr[node + 1];

    f32x8 acc0 = (f32x8){0.f,0.f,0.f,0.f,0.f,0.f,0.f,0.f};
    f32x8 acc1 = (f32x8){0.f,0.f,0.f,0.f,0.f,0.f,0.f,0.f};
    int j = beg + slot;
    for (; j + 8 < end; j += 16) {
        int s0 = csr[j];
        int s1 = csr[j + 8];
        bf16x8 v0 = *(const bf16x8*)(hb + (size_t)s0 * HID + fg * 8);
        bf16x8 v1 = *(const bf16x8*)(hb + (size_t)s1 * HID + fg * 8);
        #pragma unroll
        for (int k = 0; k < 8; k++) acc0[k] += b2f((unsigned short)v0[k]);
        #pragma unroll
        for (int k = 0; k < 8; k++) acc1[k] += b2f((unsigned short)v1[k]);
    }
    if (j < end) {
        int s0 = csr[j];
        bf16x8 v0 = *(const bf16x8*)(hb + (size_t)s0 * HID + fg * 8);
        #pragma unroll
        for (int k = 0; k < 8; k++) acc0[k] += b2f((unsigned short)v0[k]);
    }
    #pragma unroll
    for (int k = 0; k < 8; k++) {
        float a = acc0[k] + acc1[k];
        a += __shfl_xor(a, 8);
        a += __shfl_xor(a, 16);
        a += __shfl_xor(a, 32);
        acc0[k] = a;
    }
    if (slot == 0) {
        float dg = (float)(end - beg);
        dg = dg > 1.f ? dg : 1.f;
        float inv = 1.f / dg;
        bf16x8 ov;
        #pragma unroll
        for (int k = 0; k < 8; k++) ov[k] = (short)f2b(acc0[k] * inv);
        *(bf16x8*)(agghb + (size_t)node * HID + fg * 8) = ov;
    }
}

// ---------------- final MFMA: out = log_softmax([hb|agghb] @ Wt2 + b2) ----------------
__global__ __launch_bounds__(256) void final_kernel(
    const unsigned short* __restrict__ hb, const unsigned short* __restrict__ agghb,
    const unsigned short* __restrict__ Wt2, const float* __restrict__ b2,
    float* __restrict__ out, int N)
{
    __shared__ alignas(16) unsigned short sW[64 * 136];   // 17.4 KB
    const int tid = threadIdx.x;
    {
        const int4v* Wg = (const int4v*)Wt2;
        #pragma unroll
        for (int i = 0; i < 4; i++) {
            int idx16 = i * 256 + tid;            // 0..1023
            int c = idx16 >> 4;
            int k8 = idx16 & 15;
            int4v v = Wg[idx16];
            *(int4v*)&sW[c * 136 + k8 * 8] = v;
        }
    }
    __syncthreads();

    const int w = tid >> 6;
    const int lane = tid & 63;
    const int m = lane & 15;
    const int g = lane >> 4;

    const int node0 = blockIdx.x * 64;
    int arow = node0 + w * 16 + m;
    int arow_c = arow < N ? arow : 0;
    const unsigned short* hr = hb + (size_t)arow_c * HID;
    const unsigned short* ar = agghb + (size_t)arow_c * HID;

    f32x4 acc[3];
    #pragma unroll
    for (int c = 0; c < 3; c++) acc[c] = (f32x4){0.f, 0.f, 0.f, 0.f};

    #pragma unroll
    for (int ks = 0; ks < 4; ks++) {
        const int k0 = ks * 32 + g * 8;           // never straddles 64
        bf16x8 a = (k0 < 64) ? *(const bf16x8*)(hr + k0)
                             : *(const bf16x8*)(ar + (k0 - 64));
        #pragma unroll
        for (int ct = 0; ct < 3; ct++) {
            bf16x8 b = *(const bf16x8*)&sW[(ct * 16 + m) * 136 + k0];
            acc[ct] = __builtin_amdgcn_mfma_f32_16x16x32_bf16(a, b, acc[ct], 0, 0, 0);
        }
    }

    float bias[3];
    #pragma unroll
    for (int ct = 0; ct < 3; ct++) {
        int col = ct * 16 + m;
        bias[ct] = (col < NCLS) ? b2[col] : 0.f;
    }
    const bool v2 = (m < 8);

    #pragma unroll
    for (int r = 0; r < 4; r++) {
        int nd = node0 + w * 16 + g * 4 + r;
        float l0 = acc[0][r] + bias[0];
        float l1 = acc[1][r] + bias[1];
        float l2 = acc[2][r] + bias[2];
        float mx = fmaxf(l0, l1);
        if (v2) mx = fmaxf(mx, l2);
        mx = fmaxf(mx, __shfl_xor(mx, 1));
        mx = fmaxf(mx, __shfl_xor(mx, 2));
        mx = fmaxf(mx, __shfl_xor(mx, 4));
        mx = fmaxf(mx, __shfl_xor(mx, 8));
        float s = __expf(l0 - mx) + __expf(l1 - mx) + (v2 ? __expf(l2 - mx) : 0.f);
        s += __shfl_xor(s, 1);
        s += __shfl_xor(s, 2);
        s += __shfl_xor(s, 4);
        s += __shfl_xor(s, 8);
        float lse = mx + __logf(s);
        if (nd < N) {
            float* orow = out + (size_t)nd * NCLS;
            orow[m] = l0 - lse;
            orow[16 + m] = l1 - lse;
            if (v2) orow[32 + m] = l2 - lse;
        }
    }
}

extern "C" void kernel_launch(void* const* d_in, const int* in_sizes, int n_in,
                              void* d_out, int out_size, void* d_ws, size_t ws_size,
                              hipStream_t stream) {
    const float* x   = (const float*)d_in[0];
    const int*   ei  = (const int*)d_in[1];
    const float* W1l = (const float*)d_in[2];
    const float* W1r = (const float*)d_in[3];
    const float* b1  = (const float*)d_in[4];
    const float* W2l = (const float*)d_in[5];
    const float* W2r = (const float*)d_in[6];
    const float* b2  = (const float*)d_in[7];

    const int N = in_sizes[0] / F_IN;
    const int E = in_sizes[1] / 2;
    const int* src = ei;
    const int* dst = ei + E;
    const int NB = (N + TS - 1) >> TSH;    // 782 for N=100000

    // ---- workspace layout (int elements) ----
    int* wsi = (int*)d_ws;
    size_t o = 0;
    int* rowptr = wsi + o;  o += (size_t)N + 64;            // N+1
    int* btot   = wsi + o;  o += 1024;
    int* bbase  = wsi + o;  o += 1024;                      // NB+1
    int* ghist  = wsi + o;  o += (size_t)NW * GH;           // [block][tile]
    int* goff   = wsi + o;  o += (size_t)NBMAX * NW;        // [tile][block]
    o = (o + 63) & ~(size_t)63;
    unsigned* staging = (unsigned*)(wsi + o);  o += E;      // tile-grouped packed edges
    int* csr    = wsi + o;  o += E;
    o = (o + 63) & ~(size_t)63;
    unsigned short* Wt  = (unsigned short*)(wsi + o);  o += 8192;            // 128x128 bf16
    unsigned short* Wt2 = (unsigned short*)(wsi + o);  o += 4096;            // 64x128 bf16
    unsigned short* p1b = (unsigned short*)(wsi + o);  o += (size_t)32 * N;  // 64N bf16 (reused as agghb)
    unsigned short* hb  = (unsigned short*)(wsi + o);  o += (size_t)32 * N;  // 64N bf16
    unsigned short* qb  = (unsigned short*)(wsi + o);  o += (size_t)32 * N;  // 64N bf16
    unsigned short* agghb = p1b;     // alias: p1b dead after agg1
    float* out  = (float*)d_out;

    hist_kernel <<<NW, 256, 0, stream>>>(dst, ghist, E, NB);
    btot_kernel <<<NB, 256, 0, stream>>>(ghist, btot);
    bscan_kernel<<<1, 64, 0, stream>>>(btot, bbase, NB);
    boff_kernel <<<NB, 256, 0, stream>>>(ghist, bbase, goff);
    part_kernel <<<NW, 256, 0, stream>>>(src, dst, goff, staging, E, NB);
    build_kernel<<<NB, 256, 0, stream>>>(staging, bbase, rowptr, csr, N);

    wprep_kernel<<<1, 256, 0, stream>>>(W1l, W1r, W2l, W2r, Wt, Wt2);
    gemm1_kernel<<<(N + 63) / 64, 256, 0, stream>>>(x, Wt, b1, p1b, qb, N);
    agg1_kernel<<<(N + 3) / 4, 256, 0, stream>>>(rowptr, csr, p1b, qb, hb, N);
    agg2_kernel<<<(N + 3) / 4, 256, 0, stream>>>(rowptr, csr, hb, agghb, N);
    final_kernel<<<(N + 63) / 64, 256, 0, stream>>>(hb, agghb, Wt2, b2, out, N);
}